// Round 10
// baseline (184.456 us; speedup 1.0000x reference)
//
#include <hip/hip_runtime.h>
#include <stdint.h>

// Problem constants (TransformerLayer: N=6144, D=512, B=16, NMAX=512, H=8, HD=64)
#define N_NODES 6144
#define DIM 512
#define NGRAPH 16
#define NHEAD 8
#define EPSV 1e-5f

typedef unsigned short u16;
typedef short s16x4 __attribute__((ext_vector_type(4)));
typedef short s16x8 __attribute__((ext_vector_type(8)));
typedef __bf16 bf16x8 __attribute__((ext_vector_type(8)));
typedef float f32x4 __attribute__((ext_vector_type(4)));

__device__ __forceinline__ u16 f2bf(float f) {
  union { float f; unsigned u; } c{f};
  unsigned u = c.u;
  return (u16)((u + 0x7fffu + ((u >> 16) & 1u)) >> 16);  // RNE
}
__device__ __forceinline__ float bf2f(u16 v) {
  union { unsigned u; float f; } c{(unsigned)v << 16};
  return c.f;
}

__device__ __forceinline__ f32x4 mfma16(s16x8 a, s16x8 b, f32x4 c) {
  return __builtin_amdgcn_mfma_f32_16x16x32_bf16(
      __builtin_bit_cast(bf16x8, a), __builtin_bit_cast(bf16x8, b), c, 0, 0, 0);
}

__device__ __forceinline__ void gload_lds16(const void* g, void* l) {
  __builtin_amdgcn_global_load_lds(
      (const __attribute__((address_space(1))) unsigned int*)g,
      (__attribute__((address_space(3))) unsigned int*)l, 16, 0, 0);
}

// HW transpose read: lane reads 4 u16 at byte offsets {0,32,64,96} from its own
// addr; offset:128 walks to the next [4][16] subtile.
__device__ __forceinline__ s16x8 v_frag_tr(const u16* base, int u16idx) {
  s16x4 lo, hi;
  const __attribute__((address_space(3))) u16* p =
      (const __attribute__((address_space(3))) u16*)(base + u16idx);
  asm volatile("ds_read_b64_tr_b16 %0, %2\n\t"
               "ds_read_b64_tr_b16 %1, %2 offset:128\n\t"
               "s_waitcnt lgkmcnt(0)"
               : "=&v"(lo), "=&v"(hi)
               : "v"(p)
               : "memory");
  __builtin_amdgcn_sched_barrier(0);
  s16x8 r;
  r[0] = lo[0]; r[1] = lo[1]; r[2] = lo[2]; r[3] = lo[3];
  r[4] = hi[0]; r[5] = hi[1]; r[6] = hi[2]; r[7] = hi[3];
  return r;
}

// ---------------------------------------------------------------- args
struct MegaArgs {
  const float* h; const int* batch;
  const float *Wq, *bq, *Wk, *bk, *Wv, *bv, *Wo, *bo;
  const float *g1, *be1, *W1, *b1, *W2, *b2, *g2, *be2;
  float* out;
  int* starts;
  float2 *part1, *part2, *stats1;
  float* b1f;
  u16 *bt_qkv, *bt_o, *bt_1, *bt_2;
  u16 *A0, *qp, *kp, *vpb, *x1b, *x2;
};

__device__ __forceinline__ void tr_plain(const float* __restrict__ src, u16* __restrict__ dst,
                                         int C, int R, int c0, int r0, int tid, float* tile) {
  const int tx = tid & 31, ty = tid >> 5;
#pragma unroll
  for (int i = 0; i < 32; i += 8)
    tile[(ty + i) * 33 + tx] = src[(size_t)(r0 + ty + i) * C + c0 + tx];
  __syncthreads();
#pragma unroll
  for (int i = 0; i < 32; i += 8)
    dst[(size_t)(c0 + ty + i) * R + r0 + tx] = f2bf(tile[tx * 33 + ty + i]);
}

// ---------------------------------------------------------------- prep
// lb 0: starts | [1,769) Wq/Wk/Wv qkvperm | [769,3841) cvt h
__global__ void prep_kernel(MegaArgs a) {
  __shared__ float tile[32 * 33];
  const int lb = blockIdx.x, tid = threadIdx.x;
  if (lb == 0) {
    int g = tid;
    if (g > NGRAPH) return;
    if (g == NGRAPH) { a.starts[g] = N_NODES; return; }
    int lo = 0, hi = N_NODES;
    while (lo < hi) { int mid = (lo + hi) >> 1; if (a.batch[mid] < g) lo = mid + 1; else hi = mid; }
    a.starts[g] = lo;
    return;
  }
  if (lb >= 769) {  // cvt h -> bf16 (float4 per lane)
    int i = (lb - 769) * 256 + tid;
    float4 v = ((const float4*)a.h)[i];
    ushort4 o = make_ushort4(f2bf(v.x), f2bf(v.y), f2bf(v.z), f2bf(v.w));
    ((ushort4*)a.A0)[i] = o;
    return;
  }
  // QKV perm transpose: dst[v][k] = src[k][p(v)] via v(c) = ((c&7)<<6)|(c>>3)
  const int w = (lb - 1) >> 8;
  const float* src = (w == 0) ? a.Wq : (w == 1) ? a.Wk : a.Wv;
  u16* dst = a.bt_qkv + (size_t)w * 512 * 512;
  const int t = (lb - 1) & 255;
  const int c0 = (t & 15) * 32, r0 = (t >> 4) * 32;
  const int tx = tid & 31, ty = tid >> 5;
#pragma unroll
  for (int i = 0; i < 32; i += 8)
    tile[(ty + i) * 33 + tx] = src[(size_t)(r0 + ty + i) * 512 + c0 + tx];
  __syncthreads();
#pragma unroll
  for (int i = 0; i < 32; i += 8) {
    int c = c0 + ty + i;
    int v = ((c & 7) << 6) | (c >> 3);
    dst[(size_t)v * 512 + r0 + tx] = f2bf(tile[tx * 33 + ty + i]);
  }
}

// ---------------------------------------------------------------- GEMM (R7 geometry)
// C[i][j] = sum_k A[i][k] * Bt[j][k]; BK=64 staged as two stacked BK=32 halves.
// EPI 0: QKV -> oq/ok/ov [node][512] (bias via perm)
// EPI 1: ob = bf16(acc+bias+resf)             + col partials [BM=64]
// EPI 2: ob = relu(acc+bias) bf16
// EPI 3: of = acc+bias+(bf2f(resb)*st.x+st.y) + col partials [BM=64]
template <int BM, int BN, int EPI, int NBX>
__device__ void gemm_phase(int bid, int tid, u16* smem,
    const u16* __restrict__ A, const u16* __restrict__ Bt,
    const float* __restrict__ bias0, const float* __restrict__ bias1,
    const float* __restrict__ bias2, const float* __restrict__ resf,
    const u16* __restrict__ resb, const float2* __restrict__ stats,
    float2* __restrict__ part, u16* __restrict__ oq, u16* __restrict__ ok,
    u16* __restrict__ ov, float* __restrict__ of, u16* __restrict__ ob,
    int N, int K) {
  constexpr int NW_M = (BM >= 128) ? 2 : 1;
  constexpr int NW_N = 4 / NW_M;
  constexpr int WM = BM / NW_M, WN = BN / NW_N;
  constexpr int FM = WM / 16, FN = WN / 16;
  u16* As = smem;
  u16* Bs = smem + BM * 64;
  const int lane = tid & 63, wv = tid >> 6;
  const int wm = wv / NW_N, wn = wv % NW_N;
  const int row0 = (bid / NBX) * BM, col0 = (bid % NBX) * BN;

  f32x4 acc[FM][FN] = {};
  int a_off[FM], b_off[FN];
#pragma unroll
  for (int fm = 0; fm < FM; ++fm) {
    int r = wm * WM + fm * 16 + (lane & 15);
    a_off[fm] = r * 32 + (((lane >> 4) ^ ((r >> 1) & 3)) << 3);
  }
#pragma unroll
  for (int fn = 0; fn < FN; ++fn) {
    int r = wn * WN + fn * 16 + (lane & 15);
    b_off[fn] = r * 32 + (((lane >> 4) ^ ((r >> 1) & 3)) << 3);
  }

  for (int k0 = 0; k0 < K; k0 += 64) {
    __syncthreads();
#pragma unroll
    for (int is = 0; is < BM / 32; ++is) {  // two BK=32 halves stacked
      int s = is * 256 + tid;
      int kh = s / (BM * 4);
      int sh = s - kh * (BM * 4);
      int r = sh >> 2;
      int cl = (sh & 3) ^ ((r >> 1) & 3);  // pre-swizzled source (involution)
      gload_lds16(A + (size_t)(row0 + r) * K + k0 + kh * 32 + cl * 8,
                  (void*)(As + (size_t)(is * 256 + (tid & ~63)) * 8));
    }
#pragma unroll
    for (int is = 0; is < BN / 32; ++is) {
      int s = is * 256 + tid;
      int kh = s / (BN * 4);
      int sh = s - kh * (BN * 4);
      int r = sh >> 2;
      int cl = (sh & 3) ^ ((r >> 1) & 3);
      gload_lds16(Bt + (size_t)(col0 + r) * K + k0 + kh * 32 + cl * 8,
                  (void*)(Bs + (size_t)(is * 256 + (tid & ~63)) * 8));
    }
    __syncthreads();
#pragma unroll
    for (int kh = 0; kh < 2; ++kh) {
      s16x8 af[FM], bfv[FN];
#pragma unroll
      for (int fm = 0; fm < FM; ++fm) af[fm] = *(const s16x8*)(As + kh * (BM * 32) + a_off[fm]);
#pragma unroll
      for (int fn = 0; fn < FN; ++fn) bfv[fn] = *(const s16x8*)(Bs + kh * (BN * 32) + b_off[fn]);
#pragma unroll
      for (int fm = 0; fm < FM; ++fm)
#pragma unroll
        for (int fn = 0; fn < FN; ++fn)
          acc[fm][fn] = mfma16(af[fm], bfv[fn], acc[fm][fn]);
    }
  }

  // epilogue: C elem (row=(lane>>4)*4+ii, col=lane&15) per 16x16 frag
  if constexpr (EPI == 0) {
#pragma unroll
    for (int fn = 0; fn < FN; ++fn) {
      const int j = col0 + wn * WN + fn * 16 + (lane & 15);
      const int which = j >> 9;  // uniform per (wn,fn): 16-blocks never straddle 512
      u16* dst = (which == 0) ? oq : (which == 1) ? ok : ov;
      const float* bias = (which == 0) ? bias0 : (which == 1) ? bias1 : bias2;
      const int v = j & 511;
      const float bj = bias[((v & 63) << 3) | (v >> 6)];
#pragma unroll
      for (int fm = 0; fm < FM; ++fm) {
        const int ibase = row0 + wm * WM + fm * 16 + ((lane >> 4) << 2);
#pragma unroll
        for (int ii = 0; ii < 4; ++ii)
          dst[(size_t)(ibase + ii) * 512 + v] = f2bf(acc[fm][fn][ii] + bj);
      }
    }
  } else {
#pragma unroll
    for (int fn = 0; fn < FN; ++fn) {
      const int j = col0 + wn * WN + fn * 16 + (lane & 15);
      const float bj = bias0[j];
      float s = 0.f, q = 0.f;
#pragma unroll
      for (int fm = 0; fm < FM; ++fm) {
        const int ibase = row0 + wm * WM + fm * 16 + ((lane >> 4) << 2);
        if constexpr (EPI == 1) {
#pragma unroll
          for (int ii = 0; ii < 4; ++ii) {
            int i = ibase + ii;
            float val = acc[fm][fn][ii] + bj + resf[(size_t)i * N + j];
            ob[(size_t)i * N + j] = f2bf(val);
            s += val; q += val * val;
          }
        } else if constexpr (EPI == 2) {
#pragma unroll
          for (int ii = 0; ii < 4; ++ii) {
            int i = ibase + ii;
            float v = acc[fm][fn][ii] + bj;
            ob[(size_t)i * N + j] = f2bf(v > 0.f ? v : 0.f);
          }
        } else {
          const float2 st = stats[j];
#pragma unroll
          for (int ii = 0; ii < 4; ++ii) {
            int i = ibase + ii;
            float val = acc[fm][fn][ii] + bj + (bf2f(resb[(size_t)i * N + j]) * st.x + st.y);
            of[(size_t)i * N + j] = val;
            s += val; q += val * val;
          }
        }
      }
      if constexpr (EPI == 1 || EPI == 3) {  // BM=64, NW_M=1: wave covers all rows
        s += __shfl_xor(s, 16); s += __shfl_xor(s, 32);
        q += __shfl_xor(q, 16); q += __shfl_xor(q, 32);
        if ((lane >> 4) == 0) part[(size_t)(bid / NBX) * 512 + j] = make_float2(s, q);
      }
    }
  }
}

__global__ __launch_bounds__(256, 2) void qkv_kernel(MegaArgs a) {
  __shared__ __align__(16) u16 smem[(128 + 192) * 64];
  gemm_phase<128, 192, 0, 8>(blockIdx.x, threadIdx.x, smem, a.A0, a.bt_qkv,
      a.bq, a.bk, a.bv, nullptr, nullptr, nullptr, nullptr,
      a.qp, a.kp, a.vpb, nullptr, nullptr, 1536, 512);
}
__global__ __launch_bounds__(256, 2) void oproj_kernel(MegaArgs a) {
  __shared__ __align__(16) u16 smem[(64 + 128) * 64];
  gemm_phase<64, 128, 1, 4>(blockIdx.x, threadIdx.x, smem, a.A0, a.bt_o,
      a.bo, nullptr, nullptr, a.h, nullptr, nullptr, a.part1,
      nullptr, nullptr, nullptr, nullptr, a.x1b, 512, 512);
}
__global__ __launch_bounds__(256, 2) void ffn1_kernel(MegaArgs a) {
  __shared__ __align__(16) u16 smem[(128 + 128) * 64];
  gemm_phase<128, 128, 2, 8>(blockIdx.x, threadIdx.x, smem, a.x1b, a.bt_1,
      a.b1f, nullptr, nullptr, nullptr, nullptr, nullptr, nullptr,
      nullptr, nullptr, nullptr, nullptr, a.x2, 1024, 512);
}
__global__ __launch_bounds__(256, 2) void ffn2_kernel(MegaArgs a) {
  __shared__ __align__(16) u16 smem[(64 + 128) * 64];
  gemm_phase<64, 128, 3, 4>(blockIdx.x, threadIdx.x, smem, a.x2, a.bt_2,
      a.b2, nullptr, nullptr, nullptr, a.x1b, a.stats1, a.part2,
      nullptr, nullptr, nullptr, a.out, nullptr, 512, 1024);
}

// ---------------------------------------------------------------- attention (+ overlapped transposes)
// lb<1024: attn | [1024,1280) Wo operm | [1280,1792) W1 | [1792,2304) W2
__global__ __launch_bounds__(256, 2) void attnx_kernel(MegaArgs a) {
  __shared__ __align__(16) u16 smem[6144];  // Qs 2048 | Vs 2048 | Ps 2048
  const int lb = blockIdx.x, tid = threadIdx.x;
  if (lb >= 1024) {
    float* tile = (float*)smem;
    if (lb < 1280) {  // Wo: dst[j][c] = src[md(c)][j], md(c)=((c&63)<<3)|(c>>6)
      const int t = lb - 1024;
      const int c0 = (t & 15) * 32, j0 = (t >> 4) * 32;
      const int tx = tid & 31, ty = tid >> 5;
#pragma unroll
      for (int i = 0; i < 32; i += 8) {
        int c = c0 + ty + i;
        int md = ((c & 63) << 3) | (c >> 6);
        tile[(ty + i) * 33 + tx] = a.Wo[(size_t)md * 512 + j0 + tx];
      }
      __syncthreads();
#pragma unroll
      for (int i = 0; i < 32; i += 8)
        a.bt_o[(size_t)(j0 + ty + i) * 512 + c0 + tx] = f2bf(tile[tx * 33 + ty + i]);
    } else if (lb < 1792) {  // W1 plain: C=1024 -> bt_1[1024][512]
      const int t = lb - 1280;
      tr_plain(a.W1, a.bt_1, 1024, 512, (t & 31) * 32, (t >> 5) * 32, tid, tile);
    } else {  // W2 plain: C=512 -> bt_2[512][1024]
      const int t = lb - 1792;
      tr_plain(a.W2, a.bt_2, 512, 1024, (t & 15) * 32, (t >> 4) * 32, tid, tile);
    }
    return;
  }
  u16* Qs = smem;
  u16* Vs = smem + 2048;
  u16* PsB = smem + 4096;
  const int rb = lb & 7, hh = (lb >> 3) & 7, b = lb >> 6;
  const int base = a.starts[b], nb = a.starts[b + 1] - base;
  const int r0 = rb * 64;
  if (r0 >= nb) return;
  const int lane = tid & 63, wv = tid >> 6;
  const int g = lane >> 4;
  const int rloc = r0 + wv * 16 + (lane & 15);
  const u16* krow = a.kp + (size_t)(base + rloc) * 512 + hh * 64 + (g << 3);
  s16x8 ak0 = *(const s16x8*)(krow);
  s16x8 ak1 = *(const s16x8*)(krow + 32);
  f32x4 acc_av[4] = {};
  float rs[4] = {0.f, 0.f, 0.f, 0.f};
  u16* Pw = PsB + wv * 512;
  const int vm = ((tid & 63) >> 3) * 4 + ((tid >> 1) & 3);
  const int vf = wv * 16 + (tid & 1) * 8;

  for (int m0 = 0; m0 < nb; m0 += 32) {
    __syncthreads();
    { int r = tid >> 3, cl = (tid & 7) ^ (r & 7);
      gload_lds16(a.qp + (size_t)(base + m0 + r) * 512 + hh * 64 + cl * 8,
                  (void*)(Qs + (size_t)(tid & ~63) * 8)); }
    { gload_lds16(a.vpb + (size_t)(base + m0 + vm) * 512 + hh * 64 + vf,
                  (void*)(Vs + (size_t)(tid & ~63) * 8)); }
    __syncthreads();
#pragma unroll
    for (int ch = 0; ch < 2; ++ch) {
      f32x4 s = {};
#pragma unroll
      for (int kc = 0; kc < 2; ++kc) {
        const int mr = ch * 16 + (lane & 15);
        const int chunk = kc * 4 + g;
        s16x8 bq = *(const s16x8*)(Qs + mr * 64 + ((chunk ^ (mr & 7)) << 3));
        s = mfma16(kc == 0 ? ak0 : ak1, bq, s);
      }
      const int mg = m0 + ch * 16 + (lane & 15);
      const bool valid = mg < nb;
      const int c = ch * 16 + (lane & 15);
#pragma unroll
      for (int ii = 0; ii < 4; ++ii) {
        float pv = valid ? __expf(s[ii] * 0.125f) : 0.f;
        rs[ii] += pv;
        const int r = (g << 2) + ii;
        Pw[r * 32 + (((c >> 3) ^ ((r >> 1) & 3)) << 3) + (c & 7)] = f2bf(pv);
      }
    }
    const int pr = lane & 15;
    s16x8 pa = *(const s16x8*)(Pw + pr * 32 + ((g ^ ((pr >> 1) & 3)) << 3));
#pragma unroll
    for (int fb = 0; fb < 4; ++fb) {
      s16x8 bv = v_frag_tr(Vs, fb * 512 + g * 128 + (lane & 15));
      acc_av[fb] = mfma16(pa, bv, acc_av[fb]);
    }
  }
#pragma unroll
  for (int ii = 0; ii < 4; ++ii) {
    float v = rs[ii];
    v += __shfl_xor(v, 1); v += __shfl_xor(v, 2);
    v += __shfl_xor(v, 4); v += __shfl_xor(v, 8);
    rs[ii] = 1.f / v;
  }
#pragma unroll
  for (int ii = 0; ii < 4; ++ii) {
    const int rl = r0 + wv * 16 + (g << 2) + ii;
    if (rl < nb) {
      const size_t node = base + rl;
#pragma unroll
      for (int fb = 0; fb < 4; ++fb) {
        const int f = fb * 16 + (lane & 15);
        a.A0[node * 512 + hh * 64 + f] = f2bf(acc_av[fb][ii] * rs[ii]);  // av
      }
    }
  }
}

// ---------------------------------------------------------------- BN kernels
// fold: 64 blocks; reduce part1 (96 rowblocks) into LDS stats, fold 16 rows of
// bt_1 each, block 0 publishes stats1.
__global__ void fold_kernel(MegaArgs a) {
  __shared__ float2 stats_s[512];
  const int bid = blockIdx.x, tid = threadIdx.x;
  const float invn = 1.f / (float)N_NODES;
#pragma unroll
  for (int half = 0; half < 2; ++half) {
    const int c = tid + half * 256;
    float s = 0.f, q = 0.f;
#pragma unroll
    for (int p = 0; p < 96; ++p) {
      float2 v = a.part1[(size_t)p * 512 + c];
      s += v.x; q += v.y;
    }
    float m = s * invn, var = q * invn - m * m;
    float sc = a.g1[c] * rsqrtf(var + EPSV);
    stats_s[c] = make_float2(sc, a.be1[c] - m * sc);
  }
  __syncthreads();
  if (bid == 0) {
    a.stats1[tid] = stats_s[tid];
    a.stats1[tid + 256] = stats_s[tid + 256];
  }
  const int lane = tid & 63, wv = tid >> 6;
#pragma unroll
  for (int rr = 0; rr < 4; ++rr) {
    const int j = bid * 16 + wv * 4 + rr;
    u16* row = a.bt_1 + (size_t)j * 512 + lane * 8;
    s16x8 v = *(const s16x8*)row;
    s16x8 o;
    float dot = 0.f;
#pragma unroll
    for (int t = 0; t < 8; ++t) {
      float2 st = stats_s[lane * 8 + t];
      float w = bf2f((u16)v[t]);
      o[t] = (short)f2bf(w * st.x);
      dot += w * st.y;
    }
    *(s16x8*)row = o;
    dot += __shfl_xor(dot, 1);  dot += __shfl_xor(dot, 2);
    dot += __shfl_xor(dot, 4);  dot += __shfl_xor(dot, 8);
    dot += __shfl_xor(dot, 16); dot += __shfl_xor(dot, 32);
    if (lane == 0) a.b1f[j] = a.b1[j] + dot;
  }
}

// finapply: 96 blocks; reduce part2 into LDS stats, apply BN2 to out in place.
__global__ void finapply_kernel(MegaArgs a) {
  __shared__ float2 stats_s[512];
  const int bid = blockIdx.x, tid = threadIdx.x;
  const float invn = 1.f / (float)N_NODES;
#pragma unroll
  for (int half = 0; half < 2; ++half) {
    const int c = tid + half * 256;
    float s = 0.f, q = 0.f;
#pragma unroll
    for (int p = 0; p < 96; ++p) {
      float2 v = a.part2[(size_t)p * 512 + c];
      s += v.x; q += v.y;
    }
    float m = s * invn, var = q * invn - m * m;
    float sc = a.g2[c] * rsqrtf(var + EPSV);
    stats_s[c] = make_float2(sc, a.be2[c] - m * sc);
  }
  __syncthreads();
  float4* o4 = (float4*)a.out;
  const int base = bid * 8192;  // 96*8192 = 786432 = 6144*512/4
#pragma unroll 4
  for (int it = 0; it < 32; ++it) {
    const int fi = base + it * 256 + tid;
    float4 v = o4[fi];
    const int c = (fi * 4) & 511;
    float2 sa = stats_s[c], sb = stats_s[c + 1], sc2 = stats_s[c + 2], sd = stats_s[c + 3];
    o4[fi] = make_float4(v.x * sa.x + sa.y, v.y * sb.x + sb.y,
                         v.z * sc2.x + sc2.y, v.w * sd.x + sd.y);
  }
}

// ---------------------------------------------------------------- launch
extern "C" void kernel_launch(void* const* d_in, const int* in_sizes, int n_in,
                              void* d_out, int out_size, void* d_ws, size_t ws_size,
                              hipStream_t stream) {
  (void)in_sizes; (void)n_in; (void)out_size; (void)ws_size;
  char* ws = (char*)d_ws;
  size_t off = 0;
  auto alloc = [&](size_t bytes) -> void* {
    void* p = ws + off;
    off += (bytes + 255) & ~(size_t)255;
    return p;
  };

  MegaArgs a;
  a.h   = (const float*)d_in[0];
  a.batch = (const int*)d_in[1];
  a.Wq = (const float*)d_in[2];  a.bq = (const float*)d_in[3];
  a.Wk = (const float*)d_in[4];  a.bk = (const float*)d_in[5];
  a.Wv = (const float*)d_in[6];  a.bv = (const float*)d_in[7];
  a.Wo = (const float*)d_in[8];  a.bo = (const float*)d_in[9];
  a.g1 = (const float*)d_in[10]; a.be1 = (const float*)d_in[11];
  a.W1 = (const float*)d_in[12]; a.b1 = (const float*)d_in[13];
  a.W2 = (const float*)d_in[14]; a.b2 = (const float*)d_in[15];
  a.g2 = (const float*)d_in[16]; a.be2 = (const float*)d_in[17];
  a.out = (float*)d_out;

  a.starts = (int*)alloc(17 * 4);
  a.part1  = (float2*)alloc((size_t)96 * 512 * sizeof(float2));
  a.part2  = (float2*)alloc((size_t)96 * 512 * sizeof(float2));
  a.stats1 = (float2*)alloc(512 * sizeof(float2));
  a.b1f    = (float*)alloc(1024 * sizeof(float));
  a.bt_qkv = (u16*)alloc((size_t)1536 * 512 * 2);
  a.bt_o   = (u16*)alloc((size_t)512 * 512 * 2);
  a.bt_1   = (u16*)alloc((size_t)1024 * 512 * 2);
  a.bt_2   = (u16*)alloc((size_t)512 * 1024 * 2);
  a.A0  = (u16*)alloc((size_t)N_NODES * 512 * 2);          // h bf16; reused as av
  a.qp  = (u16*)alloc((size_t)(N_NODES + 64) * 512 * 2);   // with kp reused as x2
  a.kp  = (u16*)alloc((size_t)(N_NODES + 64) * 512 * 2);
  a.vpb = (u16*)alloc((size_t)(N_NODES + 64) * 512 * 2);
  a.x1b = (u16*)alloc((size_t)N_NODES * 512 * 2);          // pre-BN1 value (bf16)
  a.x2  = a.qp;  // qp+kp contiguous = 12.7MB >= 12.6MB

  prep_kernel<<<3841, 256, 0, stream>>>(a);
  qkv_kernel<<<384, 256, 0, stream>>>(a);
  attnx_kernel<<<2304, 256, 0, stream>>>(a);
  oproj_kernel<<<384, 256, 0, stream>>>(a);
  fold_kernel<<<64, 256, 0, stream>>>(a);
  ffn1_kernel<<<384, 256, 0, stream>>>(a);
  ffn2_kernel<<<384, 256, 0, stream>>>(a);
  finapply_kernel<<<96, 256, 0, stream>>>(a);
}

// Round 11
// 112.643 us; speedup vs baseline: 1.6375x; 1.6375x over previous
//
#include <hip/hip_runtime.h>
#include <stdint.h>

// Problem constants (TransformerLayer: N=6144, D=512, B=16, NMAX=512, H=8, HD=64)
#define N_NODES 6144
#define DIM 512
#define NGRAPH 16
#define NHEAD 8
#define EPSV 1e-5f

typedef unsigned short u16;
typedef short s16x4 __attribute__((ext_vector_type(4)));
typedef short s16x8 __attribute__((ext_vector_type(8)));
typedef __bf16 bf16x8 __attribute__((ext_vector_type(8)));
typedef float f32x4 __attribute__((ext_vector_type(4)));

__device__ __forceinline__ u16 f2bf(float f) {
  union { float f; unsigned u; } c{f};
  unsigned u = c.u;
  return (u16)((u + 0x7fffu + ((u >> 16) & 1u)) >> 16);  // RNE
}
__device__ __forceinline__ float bf2f(u16 v) {
  union { unsigned u; float f; } c{(unsigned)v << 16};
  return c.f;
}

__device__ __forceinline__ f32x4 mfma16(s16x8 a, s16x8 b, f32x4 c) {
  return __builtin_amdgcn_mfma_f32_16x16x32_bf16(
      __builtin_bit_cast(bf16x8, a), __builtin_bit_cast(bf16x8, b), c, 0, 0, 0);
}

__device__ __forceinline__ void gload_lds16(const void* g, void* l) {
  __builtin_amdgcn_global_load_lds(
      (const __attribute__((address_space(1))) unsigned int*)g,
      (__attribute__((address_space(3))) unsigned int*)l, 16, 0, 0);
}

// HW transpose read: lane reads 4 u16 at byte offsets {0,32,64,96} from its own
// addr; offset:128 walks to the next [4][16] subtile.
__device__ __forceinline__ s16x8 v_frag_tr(const u16* base, int u16idx) {
  s16x4 lo, hi;
  const __attribute__((address_space(3))) u16* p =
      (const __attribute__((address_space(3))) u16*)(base + u16idx);
  asm volatile("ds_read_b64_tr_b16 %0, %2\n\t"
               "ds_read_b64_tr_b16 %1, %2 offset:128\n\t"
               "s_waitcnt lgkmcnt(0)"
               : "=&v"(lo), "=&v"(hi)
               : "v"(p)
               : "memory");
  __builtin_amdgcn_sched_barrier(0);
  s16x8 r;
  r[0] = lo[0]; r[1] = lo[1]; r[2] = lo[2]; r[3] = lo[3];
  r[4] = hi[0]; r[5] = hi[1]; r[6] = hi[2]; r[7] = hi[3];
  return r;
}

// ---------------------------------------------------------------- args
struct MegaArgs {
  const float* h; const int* batch;
  const float *Wq, *bq, *Wk, *bk, *Wv, *bv, *Wo, *bo;
  const float *g1, *be1, *W1, *b1, *W2, *b2, *g2, *be2;
  float* out;
  int* starts;
  float2 *part1, *part2, *stats1, *stats2;
  float* b1f;
  u16 *bt_qkv, *bt_o, *bt_1, *bt_2;
  u16 *A0, *qp, *kp, *vpb, *x1b, *x2;
};

__device__ __forceinline__ void tr_plain(const float* __restrict__ src, u16* __restrict__ dst,
                                         int C, int R, int c0, int r0, int tid, float* tile) {
  const int tx = tid & 31, ty = tid >> 5;
#pragma unroll
  for (int i = 0; i < 32; i += 8)
    tile[(ty + i) * 33 + tx] = src[(size_t)(r0 + ty + i) * C + c0 + tx];
  __syncthreads();
#pragma unroll
  for (int i = 0; i < 32; i += 8)
    dst[(size_t)(c0 + ty + i) * R + r0 + tx] = f2bf(tile[tx * 33 + ty + i]);
}

// ---------------------------------------------------------------- prep
// lb 0: starts | [1,769) Wq/Wk/Wv qkvperm | [769,3841) cvt h
__global__ void prep_kernel(MegaArgs a) {
  __shared__ float tile[32 * 33];
  const int lb = blockIdx.x, tid = threadIdx.x;
  if (lb == 0) {
    int g = tid;
    if (g > NGRAPH) return;
    if (g == NGRAPH) { a.starts[g] = N_NODES; return; }
    int lo = 0, hi = N_NODES;
    while (lo < hi) { int mid = (lo + hi) >> 1; if (a.batch[mid] < g) lo = mid + 1; else hi = mid; }
    a.starts[g] = lo;
    return;
  }
  if (lb >= 769) {  // cvt h -> bf16 (float4 per lane)
    int i = (lb - 769) * 256 + tid;
    float4 v = ((const float4*)a.h)[i];
    ushort4 o = make_ushort4(f2bf(v.x), f2bf(v.y), f2bf(v.z), f2bf(v.w));
    ((ushort4*)a.A0)[i] = o;
    return;
  }
  // QKV perm transpose: dst[v][k] = src[k][p(v)] via v(c) = ((c&7)<<6)|(c>>3)
  const int w = (lb - 1) >> 8;
  const float* src = (w == 0) ? a.Wq : (w == 1) ? a.Wk : a.Wv;
  u16* dst = a.bt_qkv + (size_t)w * 512 * 512;
  const int t = (lb - 1) & 255;
  const int c0 = (t & 15) * 32, r0 = (t >> 4) * 32;
  const int tx = tid & 31, ty = tid >> 5;
#pragma unroll
  for (int i = 0; i < 32; i += 8)
    tile[(ty + i) * 33 + tx] = src[(size_t)(r0 + ty + i) * 512 + c0 + tx];
  __syncthreads();
#pragma unroll
  for (int i = 0; i < 32; i += 8) {
    int c = c0 + ty + i;
    int v = ((c & 7) << 6) | (c >> 3);
    dst[(size_t)v * 512 + r0 + tx] = f2bf(tile[tx * 33 + ty + i]);
  }
}

// ---------------------------------------------------------------- GEMM (R7 geometry)
// C[i][j] = sum_k A[i][k] * Bt[j][k]; BK=64 staged as two stacked BK=32 halves.
// EPI 0: QKV -> oq/ok/ov [node][512] (bias via perm)
// EPI 1: ob = bf16(acc+bias+resf)             + col partials [BM=64]
// EPI 2: ob = relu(acc+bias) bf16
// EPI 3: of = acc+bias+(bf2f(resb)*st.x+st.y) + col partials [BM=64]
template <int BM, int BN, int EPI, int NBX>
__device__ void gemm_phase(int bid, int tid, u16* smem,
    const u16* __restrict__ A, const u16* __restrict__ Bt,
    const float* __restrict__ bias0, const float* __restrict__ bias1,
    const float* __restrict__ bias2, const float* __restrict__ resf,
    const u16* __restrict__ resb, const float2* __restrict__ stats,
    float2* __restrict__ part, u16* __restrict__ oq, u16* __restrict__ ok,
    u16* __restrict__ ov, float* __restrict__ of, u16* __restrict__ ob,
    int N, int K) {
  constexpr int NW_M = (BM >= 128) ? 2 : 1;
  constexpr int NW_N = 4 / NW_M;
  constexpr int WM = BM / NW_M, WN = BN / NW_N;
  constexpr int FM = WM / 16, FN = WN / 16;
  u16* As = smem;
  u16* Bs = smem + BM * 64;
  const int lane = tid & 63, wv = tid >> 6;
  const int wm = wv / NW_N, wn = wv % NW_N;
  const int row0 = (bid / NBX) * BM, col0 = (bid % NBX) * BN;

  f32x4 acc[FM][FN] = {};
  int a_off[FM], b_off[FN];
#pragma unroll
  for (int fm = 0; fm < FM; ++fm) {
    int r = wm * WM + fm * 16 + (lane & 15);
    a_off[fm] = r * 32 + (((lane >> 4) ^ ((r >> 1) & 3)) << 3);
  }
#pragma unroll
  for (int fn = 0; fn < FN; ++fn) {
    int r = wn * WN + fn * 16 + (lane & 15);
    b_off[fn] = r * 32 + (((lane >> 4) ^ ((r >> 1) & 3)) << 3);
  }

  for (int k0 = 0; k0 < K; k0 += 64) {
    __syncthreads();
#pragma unroll
    for (int is = 0; is < BM / 32; ++is) {  // two BK=32 halves stacked
      int s = is * 256 + tid;
      int kh = s / (BM * 4);
      int sh = s - kh * (BM * 4);
      int r = sh >> 2;
      int cl = (sh & 3) ^ ((r >> 1) & 3);  // pre-swizzled source (involution)
      gload_lds16(A + (size_t)(row0 + r) * K + k0 + kh * 32 + cl * 8,
                  (void*)(As + (size_t)(is * 256 + (tid & ~63)) * 8));
    }
#pragma unroll
    for (int is = 0; is < BN / 32; ++is) {
      int s = is * 256 + tid;
      int kh = s / (BN * 4);
      int sh = s - kh * (BN * 4);
      int r = sh >> 2;
      int cl = (sh & 3) ^ ((r >> 1) & 3);
      gload_lds16(Bt + (size_t)(col0 + r) * K + k0 + kh * 32 + cl * 8,
                  (void*)(Bs + (size_t)(is * 256 + (tid & ~63)) * 8));
    }
    __syncthreads();
#pragma unroll
    for (int kh = 0; kh < 2; ++kh) {
      s16x8 af[FM], bfv[FN];
#pragma unroll
      for (int fm = 0; fm < FM; ++fm) af[fm] = *(const s16x8*)(As + kh * (BM * 32) + a_off[fm]);
#pragma unroll
      for (int fn = 0; fn < FN; ++fn) bfv[fn] = *(const s16x8*)(Bs + kh * (BN * 32) + b_off[fn]);
#pragma unroll
      for (int fm = 0; fm < FM; ++fm)
#pragma unroll
        for (int fn = 0; fn < FN; ++fn)
          acc[fm][fn] = mfma16(af[fm], bfv[fn], acc[fm][fn]);
    }
  }

  // epilogue: C elem (row=(lane>>4)*4+ii, col=lane&15) per 16x16 frag
  if constexpr (EPI == 0) {
#pragma unroll
    for (int fn = 0; fn < FN; ++fn) {
      const int j = col0 + wn * WN + fn * 16 + (lane & 15);
      const int which = j >> 9;  // uniform per (wn,fn): 16-blocks never straddle 512
      u16* dst = (which == 0) ? oq : (which == 1) ? ok : ov;
      const float* bias = (which == 0) ? bias0 : (which == 1) ? bias1 : bias2;
      const int v = j & 511;
      const float bj = bias[((v & 63) << 3) | (v >> 6)];
#pragma unroll
      for (int fm = 0; fm < FM; ++fm) {
        const int ibase = row0 + wm * WM + fm * 16 + ((lane >> 4) << 2);
#pragma unroll
        for (int ii = 0; ii < 4; ++ii)
          dst[(size_t)(ibase + ii) * 512 + v] = f2bf(acc[fm][fn][ii] + bj);
      }
    }
  } else {
#pragma unroll
    for (int fn = 0; fn < FN; ++fn) {
      const int j = col0 + wn * WN + fn * 16 + (lane & 15);
      const float bj = bias0[j];
      float s = 0.f, q = 0.f;
#pragma unroll
      for (int fm = 0; fm < FM; ++fm) {
        const int ibase = row0 + wm * WM + fm * 16 + ((lane >> 4) << 2);
        if constexpr (EPI == 1) {
#pragma unroll
          for (int ii = 0; ii < 4; ++ii) {
            int i = ibase + ii;
            float val = acc[fm][fn][ii] + bj + resf[(size_t)i * N + j];
            ob[(size_t)i * N + j] = f2bf(val);
            s += val; q += val * val;
          }
        } else if constexpr (EPI == 2) {
#pragma unroll
          for (int ii = 0; ii < 4; ++ii) {
            int i = ibase + ii;
            float v = acc[fm][fn][ii] + bj;
            ob[(size_t)i * N + j] = f2bf(v > 0.f ? v : 0.f);
          }
        } else {
          const float2 st = stats[j];
#pragma unroll
          for (int ii = 0; ii < 4; ++ii) {
            int i = ibase + ii;
            float val = acc[fm][fn][ii] + bj + (bf2f(resb[(size_t)i * N + j]) * st.x + st.y);
            of[(size_t)i * N + j] = val;
            s += val; q += val * val;
          }
        }
      }
      if constexpr (EPI == 1 || EPI == 3) {  // BM=64, NW_M=1: wave covers all rows
        s += __shfl_xor(s, 16); s += __shfl_xor(s, 32);
        q += __shfl_xor(q, 16); q += __shfl_xor(q, 32);
        if ((lane >> 4) == 0) part[(size_t)(bid / NBX) * 512 + j] = make_float2(s, q);
      }
    }
  }
}

__global__ __launch_bounds__(256, 2) void qkv_kernel(MegaArgs a) {
  __shared__ __align__(16) u16 smem[(128 + 192) * 64];
  gemm_phase<128, 192, 0, 8>(blockIdx.x, threadIdx.x, smem, a.A0, a.bt_qkv,
      a.bq, a.bk, a.bv, nullptr, nullptr, nullptr, nullptr,
      a.qp, a.kp, a.vpb, nullptr, nullptr, 1536, 512);
}
__global__ __launch_bounds__(256, 2) void oproj_kernel(MegaArgs a) {
  __shared__ __align__(16) u16 smem[(64 + 128) * 64];
  gemm_phase<64, 128, 1, 4>(blockIdx.x, threadIdx.x, smem, a.A0, a.bt_o,
      a.bo, nullptr, nullptr, a.h, nullptr, nullptr, a.part1,
      nullptr, nullptr, nullptr, nullptr, a.x1b, 512, 512);
}
__global__ __launch_bounds__(256, 2) void ffn1_kernel(MegaArgs a) {
  __shared__ __align__(16) u16 smem[(128 + 128) * 64];
  gemm_phase<128, 128, 2, 8>(blockIdx.x, threadIdx.x, smem, a.x1b, a.bt_1,
      a.b1f, nullptr, nullptr, nullptr, nullptr, nullptr, nullptr,
      nullptr, nullptr, nullptr, nullptr, a.x2, 1024, 512);
}
__global__ __launch_bounds__(256, 2) void ffn2_kernel(MegaArgs a) {
  __shared__ __align__(16) u16 smem[(64 + 128) * 64];
  gemm_phase<64, 128, 3, 4>(blockIdx.x, threadIdx.x, smem, a.x2, a.bt_2,
      a.b2, nullptr, nullptr, nullptr, a.x1b, a.stats1, a.part2,
      nullptr, nullptr, nullptr, a.out, nullptr, 512, 1024);
}

// ---------------------------------------------------------------- attention (+ overlapped transposes)
// lb<1024: attn | [1024,1280) Wo operm | [1280,1792) W1 | [1792,2304) W2
__global__ __launch_bounds__(256, 2) void attnx_kernel(MegaArgs a) {
  __shared__ __align__(16) u16 smem[6144];  // Qs 2048 | Vs 2048 | Ps 2048
  const int lb = blockIdx.x, tid = threadIdx.x;
  if (lb >= 1024) {
    float* tile = (float*)smem;
    if (lb < 1280) {  // Wo: dst[j][c] = src[md(c)][j], md(c)=((c&63)<<3)|(c>>6)
      const int t = lb - 1024;
      const int c0 = (t & 15) * 32, j0 = (t >> 4) * 32;
      const int tx = tid & 31, ty = tid >> 5;
#pragma unroll
      for (int i = 0; i < 32; i += 8) {
        int c = c0 + ty + i;
        int md = ((c & 63) << 3) | (c >> 6);
        tile[(ty + i) * 33 + tx] = a.Wo[(size_t)md * 512 + j0 + tx];
      }
      __syncthreads();
#pragma unroll
      for (int i = 0; i < 32; i += 8)
        a.bt_o[(size_t)(j0 + ty + i) * 512 + c0 + tx] = f2bf(tile[tx * 33 + ty + i]);
    } else if (lb < 1792) {  // W1 plain: C=1024 -> bt_1[1024][512]
      const int t = lb - 1280;
      tr_plain(a.W1, a.bt_1, 1024, 512, (t & 31) * 32, (t >> 5) * 32, tid, tile);
    } else {  // W2 plain: C=512 -> bt_2[512][1024]
      const int t = lb - 1792;
      tr_plain(a.W2, a.bt_2, 512, 1024, (t & 15) * 32, (t >> 4) * 32, tid, tile);
    }
    return;
  }
  u16* Qs = smem;
  u16* Vs = smem + 2048;
  u16* PsB = smem + 4096;
  const int rb = lb & 7, hh = (lb >> 3) & 7, b = lb >> 6;
  const int base = a.starts[b], nb = a.starts[b + 1] - base;
  const int r0 = rb * 64;
  if (r0 >= nb) return;
  const int lane = tid & 63, wv = tid >> 6;
  const int g = lane >> 4;
  const int rloc = r0 + wv * 16 + (lane & 15);
  const u16* krow = a.kp + (size_t)(base + rloc) * 512 + hh * 64 + (g << 3);
  s16x8 ak0 = *(const s16x8*)(krow);
  s16x8 ak1 = *(const s16x8*)(krow + 32);
  f32x4 acc_av[4] = {};
  float rs[4] = {0.f, 0.f, 0.f, 0.f};
  u16* Pw = PsB + wv * 512;
  const int vm = ((tid & 63) >> 3) * 4 + ((tid >> 1) & 3);
  const int vf = wv * 16 + (tid & 1) * 8;

  for (int m0 = 0; m0 < nb; m0 += 32) {
    __syncthreads();
    { int r = tid >> 3, cl = (tid & 7) ^ (r & 7);
      gload_lds16(a.qp + (size_t)(base + m0 + r) * 512 + hh * 64 + cl * 8,
                  (void*)(Qs + (size_t)(tid & ~63) * 8)); }
    { gload_lds16(a.vpb + (size_t)(base + m0 + vm) * 512 + hh * 64 + vf,
                  (void*)(Vs + (size_t)(tid & ~63) * 8)); }
    __syncthreads();
#pragma unroll
    for (int ch = 0; ch < 2; ++ch) {
      f32x4 s = {};
#pragma unroll
      for (int kc = 0; kc < 2; ++kc) {
        const int mr = ch * 16 + (lane & 15);
        const int chunk = kc * 4 + g;
        s16x8 bq = *(const s16x8*)(Qs + mr * 64 + ((chunk ^ (mr & 7)) << 3));
        s = mfma16(kc == 0 ? ak0 : ak1, bq, s);
      }
      const int mg = m0 + ch * 16 + (lane & 15);
      const bool valid = mg < nb;
      const int c = ch * 16 + (lane & 15);
#pragma unroll
      for (int ii = 0; ii < 4; ++ii) {
        float pv = valid ? __expf(s[ii] * 0.125f) : 0.f;
        rs[ii] += pv;
        const int r = (g << 2) + ii;
        Pw[r * 32 + (((c >> 3) ^ ((r >> 1) & 3)) << 3) + (c & 7)] = f2bf(pv);
      }
    }
    const int pr = lane & 15;
    s16x8 pa = *(const s16x8*)(Pw + pr * 32 + ((g ^ ((pr >> 1) & 3)) << 3));
#pragma unroll
    for (int fb = 0; fb < 4; ++fb) {
      s16x8 bv = v_frag_tr(Vs, fb * 512 + g * 128 + (lane & 15));
      acc_av[fb] = mfma16(pa, bv, acc_av[fb]);
    }
  }
#pragma unroll
  for (int ii = 0; ii < 4; ++ii) {
    float v = rs[ii];
    v += __shfl_xor(v, 1); v += __shfl_xor(v, 2);
    v += __shfl_xor(v, 4); v += __shfl_xor(v, 8);
    rs[ii] = 1.f / v;
  }
#pragma unroll
  for (int ii = 0; ii < 4; ++ii) {
    const int rl = r0 + wv * 16 + (g << 2) + ii;
    if (rl < nb) {
      const size_t node = base + rl;
#pragma unroll
      for (int fb = 0; fb < 4; ++fb) {
        const int f = fb * 16 + (lane & 15);
        a.A0[node * 512 + hh * 64 + f] = f2bf(acc_av[fb][ii] * rs[ii]);  // av
      }
    }
  }
}

// ---------------------------------------------------------------- batchnorm (R7-proven)
// Parallel finalize: 16 blocks x 32 cols; thread (rg,lc) sums 12 of 96 rows.
__global__ void bn_fin_kernel(const float2* __restrict__ part, const float* __restrict__ g,
                              const float* __restrict__ be, float2* __restrict__ stats) {
  __shared__ float red_s[8][32];
  __shared__ float red_q[8][32];
  const int t = threadIdx.x;
  const int lc = t & 31, rg = t >> 5;
  const int c = blockIdx.x * 32 + lc;
  float s = 0.f, q = 0.f;
#pragma unroll
  for (int k = 0; k < 12; ++k) {
    float2 v = part[(size_t)(rg + 8 * k) * 512 + c];
    s += v.x; q += v.y;
  }
  red_s[rg][lc] = s; red_q[rg][lc] = q;
  __syncthreads();
  if (rg == 0) {
#pragma unroll
    for (int r = 1; r < 8; ++r) { s += red_s[r][lc]; q += red_q[r][lc]; }
    const float inv = 1.f / (float)N_NODES;
    float m = s * inv, var = q * inv - m * m;
    float sc = g[c] * rsqrtf(var + EPSV);
    stats[c] = make_float2(sc, be[c] - m * sc);
  }
}

// Fold BN1 into FFN1 weights: bt_1[j][c] *= sc1[c]; b1f[j] = b1[j] + sum ofs1*w.
__global__ void bn1_fold_kernel(MegaArgs a) {
  const int tid = threadIdx.x, lane = tid & 63, wv = tid >> 6;
  const int j = blockIdx.x * 4 + wv;
  u16* row = a.bt_1 + (size_t)j * 512 + lane * 8;
  s16x8 v = *(const s16x8*)row;
  s16x8 o;
  float dot = 0.f;
#pragma unroll
  for (int t = 0; t < 8; ++t) {
    float2 st = a.stats1[lane * 8 + t];
    float w = bf2f((u16)v[t]);
    o[t] = (short)f2bf(w * st.x);
    dot += w * st.y;
  }
  *(s16x8*)row = o;
  dot += __shfl_xor(dot, 1);  dot += __shfl_xor(dot, 2);
  dot += __shfl_xor(dot, 4);  dot += __shfl_xor(dot, 8);
  dot += __shfl_xor(dot, 16); dot += __shfl_xor(dot, 32);
  if (lane == 0) a.b1f[j] = a.b1[j] + dot;
}

__global__ void bn_apply_f32_kernel(float* __restrict__ x, const float2* __restrict__ stats) {
  const int i = (blockIdx.x * 256 + threadIdx.x) * 4;
  float4 v = *(float4*)(x + i);
  const int c = i & 511;
  float2 sa = stats[c], sb = stats[c + 1], sc2 = stats[c + 2], sd = stats[c + 3];
  *(float4*)(x + i) = make_float4(v.x * sa.x + sa.y, v.y * sb.x + sb.y,
                                  v.z * sc2.x + sc2.y, v.w * sd.x + sd.y);
}

// ---------------------------------------------------------------- launch
extern "C" void kernel_launch(void* const* d_in, const int* in_sizes, int n_in,
                              void* d_out, int out_size, void* d_ws, size_t ws_size,
                              hipStream_t stream) {
  (void)in_sizes; (void)n_in; (void)out_size; (void)ws_size;
  char* ws = (char*)d_ws;
  size_t off = 0;
  auto alloc = [&](size_t bytes) -> void* {
    void* p = ws + off;
    off += (bytes + 255) & ~(size_t)255;
    return p;
  };

  MegaArgs a;
  a.h   = (const float*)d_in[0];
  a.batch = (const int*)d_in[1];
  a.Wq = (const float*)d_in[2];  a.bq = (const float*)d_in[3];
  a.Wk = (const float*)d_in[4];  a.bk = (const float*)d_in[5];
  a.Wv = (const float*)d_in[6];  a.bv = (const float*)d_in[7];
  a.Wo = (const float*)d_in[8];  a.bo = (const float*)d_in[9];
  a.g1 = (const float*)d_in[10]; a.be1 = (const float*)d_in[11];
  a.W1 = (const float*)d_in[12]; a.b1 = (const float*)d_in[13];
  a.W2 = (const float*)d_in[14]; a.b2 = (const float*)d_in[15];
  a.g2 = (const float*)d_in[16]; a.be2 = (const float*)d_in[17];
  a.out = (float*)d_out;

  a.starts = (int*)alloc(17 * 4);
  a.part1  = (float2*)alloc((size_t)96 * 512 * sizeof(float2));
  a.part2  = (float2*)alloc((size_t)96 * 512 * sizeof(float2));
  a.stats1 = (float2*)alloc(512 * sizeof(float2));
  a.stats2 = (float2*)alloc(512 * sizeof(float2));
  a.b1f    = (float*)alloc(1024 * sizeof(float));
  a.bt_qkv = (u16*)alloc((size_t)1536 * 512 * 2);
  a.bt_o   = (u16*)alloc((size_t)512 * 512 * 2);
  a.bt_1   = (u16*)alloc((size_t)1024 * 512 * 2);
  a.bt_2   = (u16*)alloc((size_t)512 * 1024 * 2);
  a.A0  = (u16*)alloc((size_t)N_NODES * 512 * 2);          // h bf16; reused as av
  a.qp  = (u16*)alloc((size_t)(N_NODES + 64) * 512 * 2);   // with kp reused as x2
  a.kp  = (u16*)alloc((size_t)(N_NODES + 64) * 512 * 2);
  a.vpb = (u16*)alloc((size_t)(N_NODES + 64) * 512 * 2);
  a.x1b = (u16*)alloc((size_t)N_NODES * 512 * 2);          // pre-BN1 value (bf16)
  a.x2  = a.qp;  // qp+kp contiguous = 12.7MB >= 12.6MB

  prep_kernel<<<3841, 256, 0, stream>>>(a);
  qkv_kernel<<<384, 256, 0, stream>>>(a);
  attnx_kernel<<<2304, 256, 0, stream>>>(a);
  oproj_kernel<<<384, 256, 0, stream>>>(a);
  bn_fin_kernel<<<16, 256, 0, stream>>>(a.part1, a.g1, a.be1, a.stats1);
  bn1_fold_kernel<<<256, 256, 0, stream>>>(a);
  ffn1_kernel<<<384, 256, 0, stream>>>(a);
  ffn2_kernel<<<384, 256, 0, stream>>>(a);
  bn_fin_kernel<<<16, 256, 0, stream>>>(a.part2, a.g2, a.be2, a.stats2);
  bn_apply_f32_kernel<<<3072, 256, 0, stream>>>(a.out, a.stats2);
}

// Round 12
// 105.252 us; speedup vs baseline: 1.7525x; 1.0702x over previous
//
#include <hip/hip_runtime.h>
#include <stdint.h>

// Problem constants (TransformerLayer: N=6144, D=512, B=16, NMAX=512, H=8, HD=64)
#define N_NODES 6144
#define DIM 512
#define NGRAPH 16
#define NHEAD 8
#define EPSV 1e-5f

typedef unsigned short u16;
typedef short s16x4 __attribute__((ext_vector_type(4)));
typedef short s16x8 __attribute__((ext_vector_type(8)));
typedef __bf16 bf16x8 __attribute__((ext_vector_type(8)));
typedef float f32x4 __attribute__((ext_vector_type(4)));

__device__ __forceinline__ u16 f2bf(float f) {
  union { float f; unsigned u; } c{f};
  unsigned u = c.u;
  return (u16)((u + 0x7fffu + ((u >> 16) & 1u)) >> 16);  // RNE
}
__device__ __forceinline__ float bf2f(u16 v) {
  union { unsigned u; float f; } c{(unsigned)v << 16};
  return c.f;
}

__device__ __forceinline__ f32x4 mfma16(s16x8 a, s16x8 b, f32x4 c) {
  return __builtin_amdgcn_mfma_f32_16x16x32_bf16(
      __builtin_bit_cast(bf16x8, a), __builtin_bit_cast(bf16x8, b), c, 0, 0, 0);
}

__device__ __forceinline__ void gload_lds16(const void* g, void* l) {
  __builtin_amdgcn_global_load_lds(
      (const __attribute__((address_space(1))) unsigned int*)g,
      (__attribute__((address_space(3))) unsigned int*)l, 16, 0, 0);
}

// HW transpose read: lane reads 4 u16 at byte offsets {0,32,64,96} from its own
// addr; offset:128 walks to the next [4][16] subtile.
__device__ __forceinline__ s16x8 v_frag_tr(const u16* base, int u16idx) {
  s16x4 lo, hi;
  const __attribute__((address_space(3))) u16* p =
      (const __attribute__((address_space(3))) u16*)(base + u16idx);
  asm volatile("ds_read_b64_tr_b16 %0, %2\n\t"
               "ds_read_b64_tr_b16 %1, %2 offset:128\n\t"
               "s_waitcnt lgkmcnt(0)"
               : "=&v"(lo), "=&v"(hi)
               : "v"(p)
               : "memory");
  __builtin_amdgcn_sched_barrier(0);
  s16x8 r;
  r[0] = lo[0]; r[1] = lo[1]; r[2] = lo[2]; r[3] = lo[3];
  r[4] = hi[0]; r[5] = hi[1]; r[6] = hi[2]; r[7] = hi[3];
  return r;
}

// ---------------------------------------------------------------- args
struct MegaArgs {
  const float* h; const int* batch;
  const float *Wq, *bq, *Wk, *bk, *Wv, *bv, *Wo, *bo;
  const float *g1, *be1, *W1, *b1, *W2, *b2, *g2, *be2;
  float* out;
  int* starts;
  float2 *part1, *part2, *stats1, *stats2;
  float* b1f;
  u16 *bt_qkv, *bt_o, *bt_1, *bt_2;
  u16 *A0, *qp, *kp, *vpb, *x1b, *x2;
};

__device__ __forceinline__ void tr_plain(const float* __restrict__ src, u16* __restrict__ dst,
                                         int C, int R, int c0, int r0, int tid, float* tile) {
  const int tx = tid & 31, ty = tid >> 5;
#pragma unroll
  for (int i = 0; i < 32; i += 8)
    tile[(ty + i) * 33 + tx] = src[(size_t)(r0 + ty + i) * C + c0 + tx];
  __syncthreads();
#pragma unroll
  for (int i = 0; i < 32; i += 8)
    dst[(size_t)(c0 + ty + i) * R + r0 + tx] = f2bf(tile[tx * 33 + ty + i]);
}

// ---------------------------------------------------------------- prep
// lb 0: starts | [1,769) Wq/Wk/Wv qkvperm | [769,3841) cvt h
__global__ void prep_kernel(MegaArgs a) {
  __shared__ float tile[32 * 33];
  const int lb = blockIdx.x, tid = threadIdx.x;
  if (lb == 0) {
    int g = tid;
    if (g > NGRAPH) return;
    if (g == NGRAPH) { a.starts[g] = N_NODES; return; }
    int lo = 0, hi = N_NODES;
    while (lo < hi) { int mid = (lo + hi) >> 1; if (a.batch[mid] < g) lo = mid + 1; else hi = mid; }
    a.starts[g] = lo;
    return;
  }
  if (lb >= 769) {  // cvt h -> bf16 (float4 per lane)
    int i = (lb - 769) * 256 + tid;
    float4 v = ((const float4*)a.h)[i];
    ushort4 o = make_ushort4(f2bf(v.x), f2bf(v.y), f2bf(v.z), f2bf(v.w));
    ((ushort4*)a.A0)[i] = o;
    return;
  }
  // QKV perm transpose: dst[v][k] = src[k][p(v)] via v(c) = ((c&7)<<6)|(c>>3)
  const int w = (lb - 1) >> 8;
  const float* src = (w == 0) ? a.Wq : (w == 1) ? a.Wk : a.Wv;
  u16* dst = a.bt_qkv + (size_t)w * 512 * 512;
  const int t = (lb - 1) & 255;
  const int c0 = (t & 15) * 32, r0 = (t >> 4) * 32;
  const int tx = tid & 31, ty = tid >> 5;
#pragma unroll
  for (int i = 0; i < 32; i += 8)
    tile[(ty + i) * 33 + tx] = src[(size_t)(r0 + ty + i) * 512 + c0 + tx];
  __syncthreads();
#pragma unroll
  for (int i = 0; i < 32; i += 8) {
    int c = c0 + ty + i;
    int v = ((c & 7) << 6) | (c >> 3);
    dst[(size_t)v * 512 + r0 + tx] = f2bf(tile[tx * 33 + ty + i]);
  }
}

// ---------------------------------------------------------------- GEMM (R7 geometry + T1 XCD swizzle)
// C[i][j] = sum_k A[i][k] * Bt[j][k]; BK=64 staged as two stacked BK=32 halves.
// Block decode (bijective, grid = 8*NBX*(NBY/8)): xcd=bid&7, rest=bid>>3,
// col=rest%NBX, brow=(rest/NBX)*8+xcd -> all col-blocks of a row-panel share
// bid%8 (= HW XCD) so the A-panel is HBM-fetched once per XCD, not NBX times.
// EPI 0: QKV -> oq/ok/ov [node][512] (bias via perm)
// EPI 1: ob = bf16(acc+bias+resf)             + col partials [BM=64]
// EPI 2: ob = relu(acc+bias) bf16
// EPI 3: of = acc+bias+(bf2f(resb)*st.x+st.y) + col partials [BM=64]
template <int BM, int BN, int EPI, int NBX>
__device__ void gemm_phase(int bid, int tid, u16* smem,
    const u16* __restrict__ A, const u16* __restrict__ Bt,
    const float* __restrict__ bias0, const float* __restrict__ bias1,
    const float* __restrict__ bias2, const float* __restrict__ resf,
    const u16* __restrict__ resb, const float2* __restrict__ stats,
    float2* __restrict__ part, u16* __restrict__ oq, u16* __restrict__ ok,
    u16* __restrict__ ov, float* __restrict__ of, u16* __restrict__ ob,
    int N, int K) {
  constexpr int NW_M = (BM >= 128) ? 2 : 1;
  constexpr int NW_N = 4 / NW_M;
  constexpr int WM = BM / NW_M, WN = BN / NW_N;
  constexpr int FM = WM / 16, FN = WN / 16;
  u16* As = smem;
  u16* Bs = smem + BM * 64;
  const int lane = tid & 63, wv = tid >> 6;
  const int wm = wv / NW_N, wn = wv % NW_N;
  // T1 XCD-aware decode
  const int xcd = bid & 7;
  const int rest = bid >> 3;
  const int bcol = rest % NBX;
  const int brow = (rest / NBX) * 8 + xcd;
  const int row0 = brow * BM, col0 = bcol * BN;

  f32x4 acc[FM][FN] = {};
  int a_off[FM], b_off[FN];
#pragma unroll
  for (int fm = 0; fm < FM; ++fm) {
    int r = wm * WM + fm * 16 + (lane & 15);
    a_off[fm] = r * 32 + (((lane >> 4) ^ ((r >> 1) & 3)) << 3);
  }
#pragma unroll
  for (int fn = 0; fn < FN; ++fn) {
    int r = wn * WN + fn * 16 + (lane & 15);
    b_off[fn] = r * 32 + (((lane >> 4) ^ ((r >> 1) & 3)) << 3);
  }

  for (int k0 = 0; k0 < K; k0 += 64) {
    __syncthreads();
#pragma unroll
    for (int is = 0; is < BM / 32; ++is) {  // two BK=32 halves stacked
      int s = is * 256 + tid;
      int kh = s / (BM * 4);
      int sh = s - kh * (BM * 4);
      int r = sh >> 2;
      int cl = (sh & 3) ^ ((r >> 1) & 3);  // pre-swizzled source (involution)
      gload_lds16(A + (size_t)(row0 + r) * K + k0 + kh * 32 + cl * 8,
                  (void*)(As + (size_t)(is * 256 + (tid & ~63)) * 8));
    }
#pragma unroll
    for (int is = 0; is < BN / 32; ++is) {
      int s = is * 256 + tid;
      int kh = s / (BN * 4);
      int sh = s - kh * (BN * 4);
      int r = sh >> 2;
      int cl = (sh & 3) ^ ((r >> 1) & 3);
      gload_lds16(Bt + (size_t)(col0 + r) * K + k0 + kh * 32 + cl * 8,
                  (void*)(Bs + (size_t)(is * 256 + (tid & ~63)) * 8));
    }
    __syncthreads();
#pragma unroll
    for (int kh = 0; kh < 2; ++kh) {
      s16x8 af[FM], bfv[FN];
#pragma unroll
      for (int fm = 0; fm < FM; ++fm) af[fm] = *(const s16x8*)(As + kh * (BM * 32) + a_off[fm]);
#pragma unroll
      for (int fn = 0; fn < FN; ++fn) bfv[fn] = *(const s16x8*)(Bs + kh * (BN * 32) + b_off[fn]);
#pragma unroll
      for (int fm = 0; fm < FM; ++fm)
#pragma unroll
        for (int fn = 0; fn < FN; ++fn)
          acc[fm][fn] = mfma16(af[fm], bfv[fn], acc[fm][fn]);
    }
  }

  // epilogue: C elem (row=(lane>>4)*4+ii, col=lane&15) per 16x16 frag
  if constexpr (EPI == 0) {
#pragma unroll
    for (int fn = 0; fn < FN; ++fn) {
      const int j = col0 + wn * WN + fn * 16 + (lane & 15);
      const int which = j >> 9;  // uniform per (wn,fn): 16-blocks never straddle 512
      u16* dst = (which == 0) ? oq : (which == 1) ? ok : ov;
      const float* bias = (which == 0) ? bias0 : (which == 1) ? bias1 : bias2;
      const int v = j & 511;
      const float bj = bias[((v & 63) << 3) | (v >> 6)];
#pragma unroll
      for (int fm = 0; fm < FM; ++fm) {
        const int ibase = row0 + wm * WM + fm * 16 + ((lane >> 4) << 2);
#pragma unroll
        for (int ii = 0; ii < 4; ++ii)
          dst[(size_t)(ibase + ii) * 512 + v] = f2bf(acc[fm][fn][ii] + bj);
      }
    }
  } else {
#pragma unroll
    for (int fn = 0; fn < FN; ++fn) {
      const int j = col0 + wn * WN + fn * 16 + (lane & 15);
      const float bj = bias0[j];
      float s = 0.f, q = 0.f;
#pragma unroll
      for (int fm = 0; fm < FM; ++fm) {
        const int ibase = row0 + wm * WM + fm * 16 + ((lane >> 4) << 2);
        if constexpr (EPI == 1) {
#pragma unroll
          for (int ii = 0; ii < 4; ++ii) {
            int i = ibase + ii;
            float val = acc[fm][fn][ii] + bj + resf[(size_t)i * N + j];
            ob[(size_t)i * N + j] = f2bf(val);
            s += val; q += val * val;
          }
        } else if constexpr (EPI == 2) {
#pragma unroll
          for (int ii = 0; ii < 4; ++ii) {
            int i = ibase + ii;
            float v = acc[fm][fn][ii] + bj;
            ob[(size_t)i * N + j] = f2bf(v > 0.f ? v : 0.f);
          }
        } else {
          const float2 st = stats[j];
#pragma unroll
          for (int ii = 0; ii < 4; ++ii) {
            int i = ibase + ii;
            float val = acc[fm][fn][ii] + bj + (bf2f(resb[(size_t)i * N + j]) * st.x + st.y);
            of[(size_t)i * N + j] = val;
            s += val; q += val * val;
          }
        }
      }
      if constexpr (EPI == 1 || EPI == 3) {  // BM=64, NW_M=1: wave covers all rows
        s += __shfl_xor(s, 16); s += __shfl_xor(s, 32);
        q += __shfl_xor(q, 16); q += __shfl_xor(q, 32);
        if ((lane >> 4) == 0) part[(size_t)brow * 512 + j] = make_float2(s, q);
      }
    }
  }
}

__global__ __launch_bounds__(256, 2) void qkv_kernel(MegaArgs a) {
  __shared__ __align__(16) u16 smem[(128 + 192) * 64];
  gemm_phase<128, 192, 0, 8>(blockIdx.x, threadIdx.x, smem, a.A0, a.bt_qkv,
      a.bq, a.bk, a.bv, nullptr, nullptr, nullptr, nullptr,
      a.qp, a.kp, a.vpb, nullptr, nullptr, 1536, 512);
}
__global__ __launch_bounds__(256, 2) void oproj_kernel(MegaArgs a) {
  __shared__ __align__(16) u16 smem[(64 + 128) * 64];
  gemm_phase<64, 128, 1, 4>(blockIdx.x, threadIdx.x, smem, a.A0, a.bt_o,
      a.bo, nullptr, nullptr, a.h, nullptr, nullptr, a.part1,
      nullptr, nullptr, nullptr, nullptr, a.x1b, 512, 512);
}
__global__ __launch_bounds__(256, 2) void ffn1_kernel(MegaArgs a) {
  __shared__ __align__(16) u16 smem[(128 + 128) * 64];
  gemm_phase<128, 128, 2, 8>(blockIdx.x, threadIdx.x, smem, a.x1b, a.bt_1,
      a.b1f, nullptr, nullptr, nullptr, nullptr, nullptr, nullptr,
      nullptr, nullptr, nullptr, nullptr, a.x2, 1024, 512);
}
__global__ __launch_bounds__(256, 2) void ffn2_kernel(MegaArgs a) {
  __shared__ __align__(16) u16 smem[(64 + 128) * 64];
  gemm_phase<64, 128, 3, 4>(blockIdx.x, threadIdx.x, smem, a.x2, a.bt_2,
      a.b2, nullptr, nullptr, nullptr, a.x1b, a.stats1, a.part2,
      nullptr, nullptr, nullptr, a.out, nullptr, 512, 1024);
}

// ---------------------------------------------------------------- attention (+ overlapped transposes)
// lb<1024: attn | [1024,1280) Wo operm | [1280,1792) W1 | [1792,2304) W2
__global__ __launch_bounds__(256, 2) void attnx_kernel(MegaArgs a) {
  __shared__ __align__(16) u16 smem[6144];  // Qs 2048 | Vs 2048 | Ps 2048
  const int lb = blockIdx.x, tid = threadIdx.x;
  if (lb >= 1024) {
    float* tile = (float*)smem;
    if (lb < 1280) {  // Wo: dst[j][c] = src[md(c)][j], md(c)=((c&63)<<3)|(c>>6)
      const int t = lb - 1024;
      const int c0 = (t & 15) * 32, j0 = (t >> 4) * 32;
      const int tx = tid & 31, ty = tid >> 5;
#pragma unroll
      for (int i = 0; i < 32; i += 8) {
        int c = c0 + ty + i;
        int md = ((c & 63) << 3) | (c >> 6);
        tile[(ty + i) * 33 + tx] = a.Wo[(size_t)md * 512 + j0 + tx];
      }
      __syncthreads();
#pragma unroll
      for (int i = 0; i < 32; i += 8)
        a.bt_o[(size_t)(j0 + ty + i) * 512 + c0 + tx] = f2bf(tile[tx * 33 + ty + i]);
    } else if (lb < 1792) {  // W1 plain: C=1024 -> bt_1[1024][512]
      const int t = lb - 1280;
      tr_plain(a.W1, a.bt_1, 1024, 512, (t & 31) * 32, (t >> 5) * 32, tid, tile);
    } else {  // W2 plain: C=512 -> bt_2[512][1024]
      const int t = lb - 1792;
      tr_plain(a.W2, a.bt_2, 512, 1024, (t & 15) * 32, (t >> 4) * 32, tid, tile);
    }
    return;
  }
  u16* Qs = smem;
  u16* Vs = smem + 2048;
  u16* PsB = smem + 4096;
  const int rb = lb & 7, hh = (lb >> 3) & 7, b = lb >> 6;
  const int base = a.starts[b], nb = a.starts[b + 1] - base;
  const int r0 = rb * 64;
  if (r0 >= nb) return;
  const int lane = tid & 63, wv = tid >> 6;
  const int g = lane >> 4;
  const int rloc = r0 + wv * 16 + (lane & 15);
  const u16* krow = a.kp + (size_t)(base + rloc) * 512 + hh * 64 + (g << 3);
  s16x8 ak0 = *(const s16x8*)(krow);
  s16x8 ak1 = *(const s16x8*)(krow + 32);
  f32x4 acc_av[4] = {};
  float rs[4] = {0.f, 0.f, 0.f, 0.f};
  u16* Pw = PsB + wv * 512;
  const int vm = ((tid & 63) >> 3) * 4 + ((tid >> 1) & 3);
  const int vf = wv * 16 + (tid & 1) * 8;

  for (int m0 = 0; m0 < nb; m0 += 32) {
    __syncthreads();
    { int r = tid >> 3, cl = (tid & 7) ^ (r & 7);
      gload_lds16(a.qp + (size_t)(base + m0 + r) * 512 + hh * 64 + cl * 8,
                  (void*)(Qs + (size_t)(tid & ~63) * 8)); }
    { gload_lds16(a.vpb + (size_t)(base + m0 + vm) * 512 + hh * 64 + vf,
                  (void*)(Vs + (size_t)(tid & ~63) * 8)); }
    __syncthreads();
#pragma unroll
    for (int ch = 0; ch < 2; ++ch) {
      f32x4 s = {};
#pragma unroll
      for (int kc = 0; kc < 2; ++kc) {
        const int mr = ch * 16 + (lane & 15);
        const int chunk = kc * 4 + g;
        s16x8 bq = *(const s16x8*)(Qs + mr * 64 + ((chunk ^ (mr & 7)) << 3));
        s = mfma16(kc == 0 ? ak0 : ak1, bq, s);
      }
      const int mg = m0 + ch * 16 + (lane & 15);
      const bool valid = mg < nb;
      const int c = ch * 16 + (lane & 15);
#pragma unroll
      for (int ii = 0; ii < 4; ++ii) {
        float pv = valid ? __expf(s[ii] * 0.125f) : 0.f;
        rs[ii] += pv;
        const int r = (g << 2) + ii;
        Pw[r * 32 + (((c >> 3) ^ ((r >> 1) & 3)) << 3) + (c & 7)] = f2bf(pv);
      }
    }
    const int pr = lane & 15;
    s16x8 pa = *(const s16x8*)(Pw + pr * 32 + ((g ^ ((pr >> 1) & 3)) << 3));
#pragma unroll
    for (int fb = 0; fb < 4; ++fb) {
      s16x8 bv = v_frag_tr(Vs, fb * 512 + g * 128 + (lane & 15));
      acc_av[fb] = mfma16(pa, bv, acc_av[fb]);
    }
  }
#pragma unroll
  for (int ii = 0; ii < 4; ++ii) {
    float v = rs[ii];
    v += __shfl_xor(v, 1); v += __shfl_xor(v, 2);
    v += __shfl_xor(v, 4); v += __shfl_xor(v, 8);
    rs[ii] = 1.f / v;
  }
#pragma unroll
  for (int ii = 0; ii < 4; ++ii) {
    const int rl = r0 + wv * 16 + (g << 2) + ii;
    if (rl < nb) {
      const size_t node = base + rl;
#pragma unroll
      for (int fb = 0; fb < 4; ++fb) {
        const int f = fb * 16 + (lane & 15);
        a.A0[node * 512 + hh * 64 + f] = f2bf(acc_av[fb][ii] * rs[ii]);  // av
      }
    }
  }
}

// ---------------------------------------------------------------- batchnorm (R7-proven)
// Parallel finalize: 16 blocks x 32 cols; thread (rg,lc) sums 12 of 96 rows.
__global__ void bn_fin_kernel(const float2* __restrict__ part, const float* __restrict__ g,
                              const float* __restrict__ be, float2* __restrict__ stats) {
  __shared__ float red_s[8][32];
  __shared__ float red_q[8][32];
  const int t = threadIdx.x;
  const int lc = t & 31, rg = t >> 5;
  const int c = blockIdx.x * 32 + lc;
  float s = 0.f, q = 0.f;
#pragma unroll
  for (int k = 0; k < 12; ++k) {
    float2 v = part[(size_t)(rg + 8 * k) * 512 + c];
    s += v.x; q += v.y;
  }
  red_s[rg][lc] = s; red_q[rg][lc] = q;
  __syncthreads();
  if (rg == 0) {
#pragma unroll
    for (int r = 1; r < 8; ++r) { s += red_s[r][lc]; q += red_q[r][lc]; }
    const float inv = 1.f / (float)N_NODES;
    float m = s * inv, var = q * inv - m * m;
    float sc = g[c] * rsqrtf(var + EPSV);
    stats[c] = make_float2(sc, be[c] - m * sc);
  }
}

// Fold BN1 into FFN1 weights: bt_1[j][c] *= sc1[c]; b1f[j] = b1[j] + sum ofs1*w.
__global__ void bn1_fold_kernel(MegaArgs a) {
  const int tid = threadIdx.x, lane = tid & 63, wv = tid >> 6;
  const int j = blockIdx.x * 4 + wv;
  u16* row = a.bt_1 + (size_t)j * 512 + lane * 8;
  s16x8 v = *(const s16x8*)row;
  s16x8 o;
  float dot = 0.f;
#pragma unroll
  for (int t = 0; t < 8; ++t) {
    float2 st = a.stats1[lane * 8 + t];
    float w = bf2f((u16)v[t]);
    o[t] = (short)f2bf(w * st.x);
    dot += w * st.y;
  }
  *(s16x8*)row = o;
  dot += __shfl_xor(dot, 1);  dot += __shfl_xor(dot, 2);
  dot += __shfl_xor(dot, 4);  dot += __shfl_xor(dot, 8);
  dot += __shfl_xor(dot, 16); dot += __shfl_xor(dot, 32);
  if (lane == 0) a.b1f[j] = a.b1[j] + dot;
}

__global__ void bn_apply_f32_kernel(float* __restrict__ x, const float2* __restrict__ stats) {
  const int i = (blockIdx.x * 256 + threadIdx.x) * 4;
  float4 v = *(float4*)(x + i);
  const int c = i & 511;
  float2 sa = stats[c], sb = stats[c + 1], sc2 = stats[c + 2], sd = stats[c + 3];
  *(float4*)(x + i) = make_float4(v.x * sa.x + sa.y, v.y * sb.x + sb.y,
                                  v.z * sc2.x + sc2.y, v.w * sd.x + sd.y);
}

// ---------------------------------------------------------------- launch
extern "C" void kernel_launch(void* const* d_in, const int* in_sizes, int n_in,
                              void* d_out, int out_size, void* d_ws, size_t ws_size,
                              hipStream_t stream) {
  (void)in_sizes; (void)n_in; (void)out_size; (void)ws_size;
  char* ws = (char*)d_ws;
  size_t off = 0;
  auto alloc = [&](size_t bytes) -> void* {
    void* p = ws + off;
    off += (bytes + 255) & ~(size_t)255;
    return p;
  };

  MegaArgs a;
  a.h   = (const float*)d_in[0];
  a.batch = (const int*)d_in[1];
  a.Wq = (const float*)d_in[2];  a.bq = (const float*)d_in[3];
  a.Wk = (const float*)d_in[4];  a.bk = (const float*)d_in[5];
  a.Wv = (const float*)d_in[6];  a.bv = (const float*)d_in[7];
  a.Wo = (const float*)d_in[8];  a.bo = (const float*)d_in[9];
  a.g1 = (const float*)d_in[10]; a.be1 = (const float*)d_in[11];
  a.W1 = (const float*)d_in[12]; a.b1 = (const float*)d_in[13];
  a.W2 = (const float*)d_in[14]; a.b2 = (const float*)d_in[15];
  a.g2 = (const float*)d_in[16]; a.be2 = (const float*)d_in[17];
  a.out = (float*)d_out;

  a.starts = (int*)alloc(17 * 4);
  a.part1  = (float2*)alloc((size_t)96 * 512 * sizeof(float2));
  a.part2  = (float2*)alloc((size_t)96 * 512 * sizeof(float2));
  a.stats1 = (float2*)alloc(512 * sizeof(float2));
  a.stats2 = (float2*)alloc(512 * sizeof(float2));
  a.b1f    = (float*)alloc(1024 * sizeof(float));
  a.bt_qkv = (u16*)alloc((size_t)1536 * 512 * 2);
  a.bt_o   = (u16*)alloc((size_t)512 * 512 * 2);
  a.bt_1   = (u16*)alloc((size_t)1024 * 512 * 2);
  a.bt_2   = (u16*)alloc((size_t)512 * 1024 * 2);
  a.A0  = (u16*)alloc((size_t)N_NODES * 512 * 2);          // h bf16; reused as av
  a.qp  = (u16*)alloc((size_t)(N_NODES + 64) * 512 * 2);   // with kp reused as x2
  a.kp  = (u16*)alloc((size_t)(N_NODES + 64) * 512 * 2);
  a.vpb = (u16*)alloc((size_t)(N_NODES + 64) * 512 * 2);
  a.x1b = (u16*)alloc((size_t)N_NODES * 512 * 2);          // pre-BN1 value (bf16)
  a.x2  = a.qp;  // qp+kp contiguous = 12.7MB >= 12.6MB

  prep_kernel<<<3841, 256, 0, stream>>>(a);
  qkv_kernel<<<384, 256, 0, stream>>>(a);
  attnx_kernel<<<2304, 256, 0, stream>>>(a);
  oproj_kernel<<<384, 256, 0, stream>>>(a);
  bn_fin_kernel<<<16, 256, 0, stream>>>(a.part1, a.g1, a.be1, a.stats1);
  bn1_fold_kernel<<<256, 256, 0, stream>>>(a);
  ffn1_kernel<<<384, 256, 0, stream>>>(a);
  ffn2_kernel<<<384, 256, 0, stream>>>(a);
  bn_fin_kernel<<<16, 256, 0, stream>>>(a.part2, a.g2, a.be2, a.stats2);
  bn_apply_f32_kernel<<<3072, 256, 0, stream>>>(a.out, a.stats2);
}

// Round 13
// 102.596 us; speedup vs baseline: 1.7979x; 1.0259x over previous
//
#include <hip/hip_runtime.h>
#include <stdint.h>

// Problem constants (TransformerLayer: N=6144, D=512, B=16, NMAX=512, H=8, HD=64)
#define N_NODES 6144
#define DIM 512
#define NGRAPH 16
#define NHEAD 8
#define EPSV 1e-5f

typedef unsigned short u16;
typedef short s16x4 __attribute__((ext_vector_type(4)));
typedef short s16x8 __attribute__((ext_vector_type(8)));
typedef __bf16 bf16x8 __attribute__((ext_vector_type(8)));
typedef float f32x4 __attribute__((ext_vector_type(4)));

__device__ __forceinline__ u16 f2bf(float f) {
  union { float f; unsigned u; } c{f};
  unsigned u = c.u;
  return (u16)((u + 0x7fffu + ((u >> 16) & 1u)) >> 16);  // RNE
}
__device__ __forceinline__ float bf2f(u16 v) {
  union { unsigned u; float f; } c{(unsigned)v << 16};
  return c.f;
}

__device__ __forceinline__ f32x4 mfma16(s16x8 a, s16x8 b, f32x4 c) {
  return __builtin_amdgcn_mfma_f32_16x16x32_bf16(
      __builtin_bit_cast(bf16x8, a), __builtin_bit_cast(bf16x8, b), c, 0, 0, 0);
}

__device__ __forceinline__ void gload_lds16(const void* g, void* l) {
  __builtin_amdgcn_global_load_lds(
      (const __attribute__((address_space(1))) unsigned int*)g,
      (__attribute__((address_space(3))) unsigned int*)l, 16, 0, 0);
}

// HW transpose read: lane reads 4 u16 at byte offsets {0,32,64,96} from its own
// addr; offset:128 walks to the next [4][16] subtile.
__device__ __forceinline__ s16x8 v_frag_tr(const u16* base, int u16idx) {
  s16x4 lo, hi;
  const __attribute__((address_space(3))) u16* p =
      (const __attribute__((address_space(3))) u16*)(base + u16idx);
  asm volatile("ds_read_b64_tr_b16 %0, %2\n\t"
               "ds_read_b64_tr_b16 %1, %2 offset:128\n\t"
               "s_waitcnt lgkmcnt(0)"
               : "=&v"(lo), "=&v"(hi)
               : "v"(p)
               : "memory");
  __builtin_amdgcn_sched_barrier(0);
  s16x8 r;
  r[0] = lo[0]; r[1] = lo[1]; r[2] = lo[2]; r[3] = lo[3];
  r[4] = hi[0]; r[5] = hi[1]; r[6] = hi[2]; r[7] = hi[3];
  return r;
}

// ---------------------------------------------------------------- args
struct MegaArgs {
  const float* h; const int* batch;
  const float *Wq, *bq, *Wk, *bk, *Wv, *bv, *Wo, *bo;
  const float *g1, *be1, *W1, *b1, *W2, *b2, *g2, *be2;
  float* out;
  int* starts;
  float2 *part1, *part2, *stats1, *stats2;
  float* b1f;
  u16 *bt_qkv, *bt_o, *bt_1, *bt_2;
  u16 *A0, *qp, *kp, *vpb, *x1b, *x2;
};

__device__ __forceinline__ void tr_plain(const float* __restrict__ src, u16* __restrict__ dst,
                                         int C, int R, int c0, int r0, int tid, float* tile) {
  const int tx = tid & 31, ty = tid >> 5;
#pragma unroll
  for (int i = 0; i < 32; i += 8)
    tile[(ty + i) * 33 + tx] = src[(size_t)(r0 + ty + i) * C + c0 + tx];
  __syncthreads();
#pragma unroll
  for (int i = 0; i < 32; i += 8)
    dst[(size_t)(c0 + ty + i) * R + r0 + tx] = f2bf(tile[tx * 33 + ty + i]);
}

// ---------------------------------------------------------------- prep
// lb 0: starts | [1,769) Wq/Wk/Wv qkvperm | [769,3841) cvt h
__global__ void prep_kernel(MegaArgs a) {
  __shared__ float tile[32 * 33];
  const int lb = blockIdx.x, tid = threadIdx.x;
  if (lb == 0) {
    int g = tid;
    if (g > NGRAPH) return;
    if (g == NGRAPH) { a.starts[g] = N_NODES; return; }
    int lo = 0, hi = N_NODES;
    while (lo < hi) { int mid = (lo + hi) >> 1; if (a.batch[mid] < g) lo = mid + 1; else hi = mid; }
    a.starts[g] = lo;
    return;
  }
  if (lb >= 769) {  // cvt h -> bf16 (float4 per lane)
    int i = (lb - 769) * 256 + tid;
    float4 v = ((const float4*)a.h)[i];
    ushort4 o = make_ushort4(f2bf(v.x), f2bf(v.y), f2bf(v.z), f2bf(v.w));
    ((ushort4*)a.A0)[i] = o;
    return;
  }
  // QKV perm transpose: dst[v][k] = src[k][p(v)] via v(c) = ((c&7)<<6)|(c>>3)
  const int w = (lb - 1) >> 8;
  const float* src = (w == 0) ? a.Wq : (w == 1) ? a.Wk : a.Wv;
  u16* dst = a.bt_qkv + (size_t)w * 512 * 512;
  const int t = (lb - 1) & 255;
  const int c0 = (t & 15) * 32, r0 = (t >> 4) * 32;
  const int tx = tid & 31, ty = tid >> 5;
#pragma unroll
  for (int i = 0; i < 32; i += 8)
    tile[(ty + i) * 33 + tx] = src[(size_t)(r0 + ty + i) * 512 + c0 + tx];
  __syncthreads();
#pragma unroll
  for (int i = 0; i < 32; i += 8) {
    int c = c0 + ty + i;
    int v = ((c & 7) << 6) | (c >> 3);
    dst[(size_t)v * 512 + r0 + tx] = f2bf(tile[tx * 33 + ty + i]);
  }
}

// ---------------------------------------------------------------- GEMM (R7 geometry + T1 XCD swizzle)
// C[i][j] = sum_k A[i][k] * Bt[j][k]; BK=64 staged as two stacked BK=32 halves.
// Block decode (bijective, NBY%8==0): xcd=bid&7, rest=bid>>3, col=rest%NBX,
// brow=(rest/NBX)*8+xcd -> all col-blocks of a row-panel share the XCD.
// EPI 0: QKV -> oq/ok/ov [node][512] (bias via perm)
// EPI 1: ob = bf16(acc+bias+resf)             + col partials [BM=64]
// EPI 2: ob = relu(acc+bias) bf16
// EPI 3: of = acc+bias+(bf2f(resb)*st.x+st.y) + col partials [BM=64]
template <int BM, int BN, int EPI, int NBX>
__device__ void gemm_phase(int bid, int tid, u16* smem,
    const u16* __restrict__ A, const u16* __restrict__ Bt,
    const float* __restrict__ bias0, const float* __restrict__ bias1,
    const float* __restrict__ bias2, const float* __restrict__ resf,
    const u16* __restrict__ resb, const float2* __restrict__ stats,
    float2* __restrict__ part, u16* __restrict__ oq, u16* __restrict__ ok,
    u16* __restrict__ ov, float* __restrict__ of, u16* __restrict__ ob,
    int N, int K) {
  constexpr int NW_M = (BM >= 128) ? 2 : 1;
  constexpr int NW_N = 4 / NW_M;
  constexpr int WM = BM / NW_M, WN = BN / NW_N;
  constexpr int FM = WM / 16, FN = WN / 16;
  u16* As = smem;
  u16* Bs = smem + BM * 64;
  const int lane = tid & 63, wv = tid >> 6;
  const int wm = wv / NW_N, wn = wv % NW_N;
  // T1 XCD-aware decode
  const int xcd = bid & 7;
  const int rest = bid >> 3;
  const int bcol = rest % NBX;
  const int brow = (rest / NBX) * 8 + xcd;
  const int row0 = brow * BM, col0 = bcol * BN;

  f32x4 acc[FM][FN] = {};
  int a_off[FM], b_off[FN];
#pragma unroll
  for (int fm = 0; fm < FM; ++fm) {
    int r = wm * WM + fm * 16 + (lane & 15);
    a_off[fm] = r * 32 + (((lane >> 4) ^ ((r >> 1) & 3)) << 3);
  }
#pragma unroll
  for (int fn = 0; fn < FN; ++fn) {
    int r = wn * WN + fn * 16 + (lane & 15);
    b_off[fn] = r * 32 + (((lane >> 4) ^ ((r >> 1) & 3)) << 3);
  }

  for (int k0 = 0; k0 < K; k0 += 64) {
    __syncthreads();
#pragma unroll
    for (int is = 0; is < BM / 32; ++is) {  // two BK=32 halves stacked
      int s = is * 256 + tid;
      int kh = s / (BM * 4);
      int sh = s - kh * (BM * 4);
      int r = sh >> 2;
      int cl = (sh & 3) ^ ((r >> 1) & 3);  // pre-swizzled source (involution)
      gload_lds16(A + (size_t)(row0 + r) * K + k0 + kh * 32 + cl * 8,
                  (void*)(As + (size_t)(is * 256 + (tid & ~63)) * 8));
    }
#pragma unroll
    for (int is = 0; is < BN / 32; ++is) {
      int s = is * 256 + tid;
      int kh = s / (BN * 4);
      int sh = s - kh * (BN * 4);
      int r = sh >> 2;
      int cl = (sh & 3) ^ ((r >> 1) & 3);
      gload_lds16(Bt + (size_t)(col0 + r) * K + k0 + kh * 32 + cl * 8,
                  (void*)(Bs + (size_t)(is * 256 + (tid & ~63)) * 8));
    }
    __syncthreads();
#pragma unroll
    for (int kh = 0; kh < 2; ++kh) {
      s16x8 af[FM], bfv[FN];
#pragma unroll
      for (int fm = 0; fm < FM; ++fm) af[fm] = *(const s16x8*)(As + kh * (BM * 32) + a_off[fm]);
#pragma unroll
      for (int fn = 0; fn < FN; ++fn) bfv[fn] = *(const s16x8*)(Bs + kh * (BN * 32) + b_off[fn]);
#pragma unroll
      for (int fm = 0; fm < FM; ++fm)
#pragma unroll
        for (int fn = 0; fn < FN; ++fn)
          acc[fm][fn] = mfma16(af[fm], bfv[fn], acc[fm][fn]);
    }
  }

  // epilogue: C elem (row=(lane>>4)*4+ii, col=lane&15) per 16x16 frag
  if constexpr (EPI == 0) {
#pragma unroll
    for (int fn = 0; fn < FN; ++fn) {
      const int j = col0 + wn * WN + fn * 16 + (lane & 15);
      const int which = j >> 9;  // uniform per (wn,fn): 16-blocks never straddle 512
      u16* dst = (which == 0) ? oq : (which == 1) ? ok : ov;
      const float* bias = (which == 0) ? bias0 : (which == 1) ? bias1 : bias2;
      const int v = j & 511;
      const float bj = bias[((v & 63) << 3) | (v >> 6)];
#pragma unroll
      for (int fm = 0; fm < FM; ++fm) {
        const int ibase = row0 + wm * WM + fm * 16 + ((lane >> 4) << 2);
#pragma unroll
        for (int ii = 0; ii < 4; ++ii)
          dst[(size_t)(ibase + ii) * 512 + v] = f2bf(acc[fm][fn][ii] + bj);
      }
    }
  } else {
#pragma unroll
    for (int fn = 0; fn < FN; ++fn) {
      const int j = col0 + wn * WN + fn * 16 + (lane & 15);
      const float bj = bias0[j];
      float s = 0.f, q = 0.f;
#pragma unroll
      for (int fm = 0; fm < FM; ++fm) {
        const int ibase = row0 + wm * WM + fm * 16 + ((lane >> 4) << 2);
        if constexpr (EPI == 1) {
#pragma unroll
          for (int ii = 0; ii < 4; ++ii) {
            int i = ibase + ii;
            float val = acc[fm][fn][ii] + bj + resf[(size_t)i * N + j];
            ob[(size_t)i * N + j] = f2bf(val);
            s += val; q += val * val;
          }
        } else if constexpr (EPI == 2) {
#pragma unroll
          for (int ii = 0; ii < 4; ++ii) {
            int i = ibase + ii;
            float v = acc[fm][fn][ii] + bj;
            ob[(size_t)i * N + j] = f2bf(v > 0.f ? v : 0.f);
          }
        } else {
          const float2 st = stats[j];
#pragma unroll
          for (int ii = 0; ii < 4; ++ii) {
            int i = ibase + ii;
            float val = acc[fm][fn][ii] + bj + (bf2f(resb[(size_t)i * N + j]) * st.x + st.y);
            of[(size_t)i * N + j] = val;
            s += val; q += val * val;
          }
        }
      }
      if constexpr (EPI == 1 || EPI == 3) {  // BM=64, NW_M=1: wave covers all rows
        s += __shfl_xor(s, 16); s += __shfl_xor(s, 32);
        q += __shfl_xor(q, 16); q += __shfl_xor(q, 32);
        if ((lane >> 4) == 0) part[(size_t)brow * 512 + j] = make_float2(s, q);
      }
    }
  }
}

// QKV: 128x96 tile -> grid 768 = exactly 3 blocks/CU (grid quantization fix)
__global__ __launch_bounds__(256, 3) void qkv_kernel(MegaArgs a) {
  __shared__ __align__(16) u16 smem[(128 + 96) * 64];
  gemm_phase<128, 96, 0, 16>(blockIdx.x, threadIdx.x, smem, a.A0, a.bt_qkv,
      a.bq, a.bk, a.bv, nullptr, nullptr, nullptr, nullptr,
      a.qp, a.kp, a.vpb, nullptr, nullptr, 1536, 512);
}
__global__ __launch_bounds__(256, 2) void oproj_kernel(MegaArgs a) {
  __shared__ __align__(16) u16 smem[(64 + 128) * 64];
  gemm_phase<64, 128, 1, 4>(blockIdx.x, threadIdx.x, smem, a.A0, a.bt_o,
      a.bo, nullptr, nullptr, a.h, nullptr, nullptr, a.part1,
      nullptr, nullptr, nullptr, nullptr, a.x1b, 512, 512);
}
__global__ __launch_bounds__(256, 2) void ffn1_kernel(MegaArgs a) {
  __shared__ __align__(16) u16 smem[(128 + 128) * 64];
  gemm_phase<128, 128, 2, 8>(blockIdx.x, threadIdx.x, smem, a.x1b, a.bt_1,
      a.b1f, nullptr, nullptr, nullptr, nullptr, nullptr, nullptr,
      nullptr, nullptr, nullptr, nullptr, a.x2, 1024, 512);
}
__global__ __launch_bounds__(256, 2) void ffn2_kernel(MegaArgs a) {
  __shared__ __align__(16) u16 smem[(64 + 128) * 64];
  gemm_phase<64, 128, 3, 4>(blockIdx.x, threadIdx.x, smem, a.x2, a.bt_2,
      a.b2, nullptr, nullptr, nullptr, a.x1b, a.stats1, a.part2,
      nullptr, nullptr, nullptr, a.out, nullptr, 512, 1024);
}

// ---------------------------------------------------------------- attention (+ overlapped transposes)
// lb<1024: attn | [1024,1280) Wo operm | [1280,1792) W1 | [1792,2304) W2
__global__ __launch_bounds__(256, 2) void attnx_kernel(MegaArgs a) {
  __shared__ __align__(16) u16 smem[6144];  // Qs 2048 | Vs 2048 | Ps 2048
  const int lb = blockIdx.x, tid = threadIdx.x;
  if (lb >= 1024) {
    float* tile = (float*)smem;
    if (lb < 1280) {  // Wo: dst[j][c] = src[md(c)][j], md(c)=((c&63)<<3)|(c>>6)
      const int t = lb - 1024;
      const int c0 = (t & 15) * 32, j0 = (t >> 4) * 32;
      const int tx = tid & 31, ty = tid >> 5;
#pragma unroll
      for (int i = 0; i < 32; i += 8) {
        int c = c0 + ty + i;
        int md = ((c & 63) << 3) | (c >> 6);
        tile[(ty + i) * 33 + tx] = a.Wo[(size_t)md * 512 + j0 + tx];
      }
      __syncthreads();
#pragma unroll
      for (int i = 0; i < 32; i += 8)
        a.bt_o[(size_t)(j0 + ty + i) * 512 + c0 + tx] = f2bf(tile[tx * 33 + ty + i]);
    } else if (lb < 1792) {  // W1 plain: C=1024 -> bt_1[1024][512]
      const int t = lb - 1280;
      tr_plain(a.W1, a.bt_1, 1024, 512, (t & 31) * 32, (t >> 5) * 32, tid, tile);
    } else {  // W2 plain: C=512 -> bt_2[512][1024]
      const int t = lb - 1792;
      tr_plain(a.W2, a.bt_2, 512, 1024, (t & 15) * 32, (t >> 4) * 32, tid, tile);
    }
    return;
  }
  u16* Qs = smem;
  u16* Vs = smem + 2048;
  u16* PsB = smem + 4096;
  const int rb = lb & 7, hh = (lb >> 3) & 7, b = lb >> 6;
  const int base = a.starts[b], nb = a.starts[b + 1] - base;
  const int r0 = rb * 64;
  if (r0 >= nb) return;
  const int lane = tid & 63, wv = tid >> 6;
  const int g = lane >> 4;
  const int rloc = r0 + wv * 16 + (lane & 15);
  const u16* krow = a.kp + (size_t)(base + rloc) * 512 + hh * 64 + (g << 3);
  s16x8 ak0 = *(const s16x8*)(krow);
  s16x8 ak1 = *(const s16x8*)(krow + 32);
  f32x4 acc_av[4] = {};
  float rs[4] = {0.f, 0.f, 0.f, 0.f};
  u16* Pw = PsB + wv * 512;
  const int vm = ((tid & 63) >> 3) * 4 + ((tid >> 1) & 3);
  const int vf = wv * 16 + (tid & 1) * 8;

  for (int m0 = 0; m0 < nb; m0 += 32) {
    __syncthreads();
    { int r = tid >> 3, cl = (tid & 7) ^ (r & 7);
      gload_lds16(a.qp + (size_t)(base + m0 + r) * 512 + hh * 64 + cl * 8,
                  (void*)(Qs + (size_t)(tid & ~63) * 8)); }
    { gload_lds16(a.vpb + (size_t)(base + m0 + vm) * 512 + hh * 64 + vf,
                  (void*)(Vs + (size_t)(tid & ~63) * 8)); }
    __syncthreads();
#pragma unroll
    for (int ch = 0; ch < 2; ++ch) {
      f32x4 s = {};
#pragma unroll
      for (int kc = 0; kc < 2; ++kc) {
        const int mr = ch * 16 + (lane & 15);
        const int chunk = kc * 4 + g;
        s16x8 bq = *(const s16x8*)(Qs + mr * 64 + ((chunk ^ (mr & 7)) << 3));
        s = mfma16(kc == 0 ? ak0 : ak1, bq, s);
      }
      const int mg = m0 + ch * 16 + (lane & 15);
      const bool valid = mg < nb;
      const int c = ch * 16 + (lane & 15);
#pragma unroll
      for (int ii = 0; ii < 4; ++ii) {
        float pv = valid ? __expf(s[ii] * 0.125f) : 0.f;
        rs[ii] += pv;
        const int r = (g << 2) + ii;
        Pw[r * 32 + (((c >> 3) ^ ((r >> 1) & 3)) << 3) + (c & 7)] = f2bf(pv);
      }
    }
    const int pr = lane & 15;
    s16x8 pa = *(const s16x8*)(Pw + pr * 32 + ((g ^ ((pr >> 1) & 3)) << 3));
#pragma unroll
    for (int fb = 0; fb < 4; ++fb) {
      s16x8 bv = v_frag_tr(Vs, fb * 512 + g * 128 + (lane & 15));
      acc_av[fb] = mfma16(pa, bv, acc_av[fb]);
    }
  }
#pragma unroll
  for (int ii = 0; ii < 4; ++ii) {
    float v = rs[ii];
    v += __shfl_xor(v, 1); v += __shfl_xor(v, 2);
    v += __shfl_xor(v, 4); v += __shfl_xor(v, 8);
    rs[ii] = 1.f / v;
  }
#pragma unroll
  for (int ii = 0; ii < 4; ++ii) {
    const int rl = r0 + wv * 16 + (g << 2) + ii;
    if (rl < nb) {
      const size_t node = base + rl;
#pragma unroll
      for (int fb = 0; fb < 4; ++fb) {
        const int f = fb * 16 + (lane & 15);
        a.A0[node * 512 + hh * 64 + f] = f2bf(acc_av[fb][ii] * rs[ii]);  // av
      }
    }
  }
}

// ---------------------------------------------------------------- batchnorm (R7-proven)
// Parallel finalize: 16 blocks x 32 cols; thread (rg,lc) sums 12 of 96 rows.
__global__ void bn_fin_kernel(const float2* __restrict__ part, const float* __restrict__ g,
                              const float* __restrict__ be, float2* __restrict__ stats) {
  __shared__ float red_s[8][32];
  __shared__ float red_q[8][32];
  const int t = threadIdx.x;
  const int lc = t & 31, rg = t >> 5;
  const int c = blockIdx.x * 32 + lc;
  float s = 0.f, q = 0.f;
#pragma unroll
  for (int k = 0; k < 12; ++k) {
    float2 v = part[(size_t)(rg + 8 * k) * 512 + c];
    s += v.x; q += v.y;
  }
  red_s[rg][lc] = s; red_q[rg][lc] = q;
  __syncthreads();
  if (rg == 0) {
#pragma unroll
    for (int r = 1; r < 8; ++r) { s += red_s[r][lc]; q += red_q[r][lc]; }
    const float inv = 1.f / (float)N_NODES;
    float m = s * inv, var = q * inv - m * m;
    float sc = g[c] * rsqrtf(var + EPSV);
    stats[c] = make_float2(sc, be[c] - m * sc);
  }
}

// Fold BN1 into FFN1 weights: bt_1[j][c] *= sc1[c]; b1f[j] = b1[j] + sum ofs1*w.
__global__ void bn1_fold_kernel(MegaArgs a) {
  const int tid = threadIdx.x, lane = tid & 63, wv = tid >> 6;
  const int j = blockIdx.x * 4 + wv;
  u16* row = a.bt_1 + (size_t)j * 512 + lane * 8;
  s16x8 v = *(const s16x8*)row;
  s16x8 o;
  float dot = 0.f;
#pragma unroll
  for (int t = 0; t < 8; ++t) {
    float2 st = a.stats1[lane * 8 + t];
    float w = bf2f((u16)v[t]);
    o[t] = (short)f2bf(w * st.x);
    dot += w * st.y;
  }
  *(s16x8*)row = o;
  dot += __shfl_xor(dot, 1);  dot += __shfl_xor(dot, 2);
  dot += __shfl_xor(dot, 4);  dot += __shfl_xor(dot, 8);
  dot += __shfl_xor(dot, 16); dot += __shfl_xor(dot, 32);
  if (lane == 0) a.b1f[j] = a.b1[j] + dot;
}

__global__ void bn_apply_f32_kernel(float* __restrict__ x, const float2* __restrict__ stats) {
  const int i = (blockIdx.x * 256 + threadIdx.x) * 4;
  float4 v = *(float4*)(x + i);
  const int c = i & 511;
  float2 sa = stats[c], sb = stats[c + 1], sc2 = stats[c + 2], sd = stats[c + 3];
  *(float4*)(x + i) = make_float4(v.x * sa.x + sa.y, v.y * sb.x + sb.y,
                                  v.z * sc2.x + sc2.y, v.w * sd.x + sd.y);
}

// ---------------------------------------------------------------- launch
extern "C" void kernel_launch(void* const* d_in, const int* in_sizes, int n_in,
                              void* d_out, int out_size, void* d_ws, size_t ws_size,
                              hipStream_t stream) {
  (void)in_sizes; (void)n_in; (void)out_size; (void)ws_size;
  char* ws = (char*)d_ws;
  size_t off = 0;
  auto alloc = [&](size_t bytes) -> void* {
    void* p = ws + off;
    off += (bytes + 255) & ~(size_t)255;
    return p;
  };

  MegaArgs a;
  a.h   = (const float*)d_in[0];
  a.batch = (const int*)d_in[1];
  a.Wq = (const float*)d_in[2];  a.bq = (const float*)d_in[3];
  a.Wk = (const float*)d_in[4];  a.bk = (const float*)d_in[5];
  a.Wv = (const float*)d_in[6];  a.bv = (const float*)d_in[7];
  a.Wo = (const float*)d_in[8];  a.bo = (const float*)d_in[9];
  a.g1 = (const float*)d_in[10]; a.be1 = (const float*)d_in[11];
  a.W1 = (const float*)d_in[12]; a.b1 = (const float*)d_in[13];
  a.W2 = (const float*)d_in[14]; a.b2 = (const float*)d_in[15];
  a.g2 = (const float*)d_in[16]; a.be2 = (const float*)d_in[17];
  a.out = (float*)d_out;

  a.starts = (int*)alloc(17 * 4);
  a.part1  = (float2*)alloc((size_t)96 * 512 * sizeof(float2));
  a.part2  = (float2*)alloc((size_t)96 * 512 * sizeof(float2));
  a.stats1 = (float2*)alloc(512 * sizeof(float2));
  a.stats2 = (float2*)alloc(512 * sizeof(float2));
  a.b1f    = (float*)alloc(1024 * sizeof(float));
  a.bt_qkv = (u16*)alloc((size_t)1536 * 512 * 2);
  a.bt_o   = (u16*)alloc((size_t)512 * 512 * 2);
  a.bt_1   = (u16*)alloc((size_t)1024 * 512 * 2);
  a.bt_2   = (u16*)alloc((size_t)512 * 1024 * 2);
  a.A0  = (u16*)alloc((size_t)N_NODES * 512 * 2);          // h bf16; reused as av
  a.qp  = (u16*)alloc((size_t)(N_NODES + 64) * 512 * 2);   // with kp reused as x2
  a.kp  = (u16*)alloc((size_t)(N_NODES + 64) * 512 * 2);
  a.vpb = (u16*)alloc((size_t)(N_NODES + 64) * 512 * 2);
  a.x1b = (u16*)alloc((size_t)N_NODES * 512 * 2);          // pre-BN1 value (bf16)
  a.x2  = a.qp;  // qp+kp contiguous = 12.7MB >= 12.6MB

  prep_kernel<<<3841, 256, 0, stream>>>(a);
  qkv_kernel<<<768, 256, 0, stream>>>(a);
  attnx_kernel<<<2304, 256, 0, stream>>>(a);
  oproj_kernel<<<384, 256, 0, stream>>>(a);
  bn_fin_kernel<<<16, 256, 0, stream>>>(a.part1, a.g1, a.be1, a.stats1);
  bn1_fold_kernel<<<256, 256, 0, stream>>>(a);
  ffn1_kernel<<<384, 256, 0, stream>>>(a);
  ffn2_kernel<<<384, 256, 0, stream>>>(a);
  bn_fin_kernel<<<16, 256, 0, stream>>>(a.part2, a.g2, a.be2, a.stats2);
  bn_apply_f32_kernel<<<3072, 256, 0, stream>>>(a.out, a.stats2);
}

// Round 14
// 97.384 us; speedup vs baseline: 1.8941x; 1.0535x over previous
//
#include <hip/hip_runtime.h>
#include <stdint.h>

// Problem constants (TransformerLayer: N=6144, D=512, B=16, NMAX=512, H=8, HD=64)
#define N_NODES 6144
#define DIM 512
#define NGRAPH 16
#define NHEAD 8
#define EPSV 1e-5f

typedef unsigned short u16;
typedef short s16x4 __attribute__((ext_vector_type(4)));
typedef short s16x8 __attribute__((ext_vector_type(8)));
typedef __bf16 bf16x8 __attribute__((ext_vector_type(8)));
typedef float f32x4 __attribute__((ext_vector_type(4)));

__device__ __forceinline__ u16 f2bf(float f) {
  union { float f; unsigned u; } c{f};
  unsigned u = c.u;
  return (u16)((u + 0x7fffu + ((u >> 16) & 1u)) >> 16);  // RNE
}
__device__ __forceinline__ float bf2f(u16 v) {
  union { unsigned u; float f; } c{(unsigned)v << 16};
  return c.f;
}

__device__ __forceinline__ f32x4 mfma16(s16x8 a, s16x8 b, f32x4 c) {
  return __builtin_amdgcn_mfma_f32_16x16x32_bf16(
      __builtin_bit_cast(bf16x8, a), __builtin_bit_cast(bf16x8, b), c, 0, 0, 0);
}

__device__ __forceinline__ void gload_lds16(const void* g, void* l) {
  __builtin_amdgcn_global_load_lds(
      (const __attribute__((address_space(1))) unsigned int*)g,
      (__attribute__((address_space(3))) unsigned int*)l, 16, 0, 0);
}

// HW transpose read: lane reads 4 u16 at byte offsets {0,32,64,96} from its own
// addr; offset:128 walks to the next [4][16] subtile.
__device__ __forceinline__ s16x8 v_frag_tr(const u16* base, int u16idx) {
  s16x4 lo, hi;
  const __attribute__((address_space(3))) u16* p =
      (const __attribute__((address_space(3))) u16*)(base + u16idx);
  asm volatile("ds_read_b64_tr_b16 %0, %2\n\t"
               "ds_read_b64_tr_b16 %1, %2 offset:128\n\t"
               "s_waitcnt lgkmcnt(0)"
               : "=&v"(lo), "=&v"(hi)
               : "v"(p)
               : "memory");
  __builtin_amdgcn_sched_barrier(0);
  s16x8 r;
  r[0] = lo[0]; r[1] = lo[1]; r[2] = lo[2]; r[3] = lo[3];
  r[4] = hi[0]; r[5] = hi[1]; r[6] = hi[2]; r[7] = hi[3];
  return r;
}

// ---------------------------------------------------------------- args
struct MegaArgs {
  const float* h; const int* batch;
  const float *Wq, *bq, *Wk, *bk, *Wv, *bv, *Wo, *bo;
  const float *g1, *be1, *W1, *b1, *W2, *b2, *g2, *be2;
  float* out;
  int* starts;
  float2 *part1, *part2, *stats1, *stats2;
  float* b1f;
  u16 *bt_qkv, *bt_o, *bt_1, *bt_2;
  u16 *A0, *qp, *kp, *vpb, *x1b, *x2;
};

__device__ __forceinline__ void tr_plain(const float* __restrict__ src, u16* __restrict__ dst,
                                         int C, int R, int c0, int r0, int tid, float* tile) {
  const int tx = tid & 31, ty = tid >> 5;
#pragma unroll
  for (int i = 0; i < 32; i += 8)
    tile[(ty + i) * 33 + tx] = src[(size_t)(r0 + ty + i) * C + c0 + tx];
  __syncthreads();
#pragma unroll
  for (int i = 0; i < 32; i += 8)
    dst[(size_t)(c0 + ty + i) * R + r0 + tx] = f2bf(tile[tx * 33 + ty + i]);
}

// ---------------------------------------------------------------- prep
// lb 0: starts | [1,769) Wq/Wk/Wv qkvperm | [769,3841) cvt h
__global__ void prep_kernel(MegaArgs a) {
  __shared__ float tile[32 * 33];
  const int lb = blockIdx.x, tid = threadIdx.x;
  if (lb == 0) {
    int g = tid;
    if (g > NGRAPH) return;
    if (g == NGRAPH) { a.starts[g] = N_NODES; return; }
    int lo = 0, hi = N_NODES;
    while (lo < hi) { int mid = (lo + hi) >> 1; if (a.batch[mid] < g) lo = mid + 1; else hi = mid; }
    a.starts[g] = lo;
    return;
  }
  if (lb >= 769) {  // cvt h -> bf16 (float4 per lane)
    int i = (lb - 769) * 256 + tid;
    float4 v = ((const float4*)a.h)[i];
    ushort4 o = make_ushort4(f2bf(v.x), f2bf(v.y), f2bf(v.z), f2bf(v.w));
    ((ushort4*)a.A0)[i] = o;
    return;
  }
  // QKV perm transpose: dst[v][k] = src[k][p(v)] via v(c) = ((c&7)<<6)|(c>>3)
  const int w = (lb - 1) >> 8;
  const float* src = (w == 0) ? a.Wq : (w == 1) ? a.Wk : a.Wv;
  u16* dst = a.bt_qkv + (size_t)w * 512 * 512;
  const int t = (lb - 1) & 255;
  const int c0 = (t & 15) * 32, r0 = (t >> 4) * 32;
  const int tx = tid & 31, ty = tid >> 5;
#pragma unroll
  for (int i = 0; i < 32; i += 8)
    tile[(ty + i) * 33 + tx] = src[(size_t)(r0 + ty + i) * 512 + c0 + tx];
  __syncthreads();
#pragma unroll
  for (int i = 0; i < 32; i += 8) {
    int c = c0 + ty + i;
    int v = ((c & 7) << 6) | (c >> 3);
    dst[(size_t)v * 512 + r0 + tx] = f2bf(tile[tx * 33 + ty + i]);
  }
}

// ---------------------------------------------------------------- GEMM (R7 K-loop + T1 XCD swizzle)
// C[i][j] = sum_k A[i][k] * Bt[j][k]; BK=64 staged as two stacked BK=32 halves.
// Block decode (bijective, NBY%8==0): xcd=bid&7, rest=bid>>3, col=rest%NBX,
// brow=(rest/NBX)*8+xcd -> all col-blocks of a row-panel share the XCD.
// EPI 0: QKV -> oq/ok/ov [node][512] (bias via perm)
// EPI 1: ob = bf16(acc+bias+resf)             + col partials [BM=64]
// EPI 2: ob = relu(acc+bias) bf16
// EPI 3: of = acc+bias+(bf2f(resb)*st.x+st.y) + col partials [BM=64]
template <int BM, int BN, int EPI, int NBX>
__device__ void gemm_phase(int bid, int tid, u16* smem,
    const u16* __restrict__ A, const u16* __restrict__ Bt,
    const float* __restrict__ bias0, const float* __restrict__ bias1,
    const float* __restrict__ bias2, const float* __restrict__ resf,
    const u16* __restrict__ resb, const float2* __restrict__ stats,
    float2* __restrict__ part, u16* __restrict__ oq, u16* __restrict__ ok,
    u16* __restrict__ ov, float* __restrict__ of, u16* __restrict__ ob,
    int N, int K) {
  constexpr int NW_M = (BM >= 128) ? 2 : 1;
  constexpr int NW_N = 4 / NW_M;
  constexpr int WM = BM / NW_M, WN = BN / NW_N;
  constexpr int FM = WM / 16, FN = WN / 16;
  u16* As = smem;
  u16* Bs = smem + BM * 64;
  const int lane = tid & 63, wv = tid >> 6;
  const int wm = wv / NW_N, wn = wv % NW_N;
  // T1 XCD-aware decode
  const int xcd = bid & 7;
  const int rest = bid >> 3;
  const int bcol = rest % NBX;
  const int brow = (rest / NBX) * 8 + xcd;
  const int row0 = brow * BM, col0 = bcol * BN;

  f32x4 acc[FM][FN] = {};
  int a_off[FM], b_off[FN];
#pragma unroll
  for (int fm = 0; fm < FM; ++fm) {
    int r = wm * WM + fm * 16 + (lane & 15);
    a_off[fm] = r * 32 + (((lane >> 4) ^ ((r >> 1) & 3)) << 3);
  }
#pragma unroll
  for (int fn = 0; fn < FN; ++fn) {
    int r = wn * WN + fn * 16 + (lane & 15);
    b_off[fn] = r * 32 + (((lane >> 4) ^ ((r >> 1) & 3)) << 3);
  }

  for (int k0 = 0; k0 < K; k0 += 64) {
    __syncthreads();
#pragma unroll
    for (int is = 0; is < BM / 32; ++is) {  // two BK=32 halves stacked
      int s = is * 256 + tid;
      int kh = s / (BM * 4);
      int sh = s - kh * (BM * 4);
      int r = sh >> 2;
      int cl = (sh & 3) ^ ((r >> 1) & 3);  // pre-swizzled source (involution)
      gload_lds16(A + (size_t)(row0 + r) * K + k0 + kh * 32 + cl * 8,
                  (void*)(As + (size_t)(is * 256 + (tid & ~63)) * 8));
    }
#pragma unroll
    for (int is = 0; is < BN / 32; ++is) {
      int s = is * 256 + tid;
      int kh = s / (BN * 4);
      int sh = s - kh * (BN * 4);
      int r = sh >> 2;
      int cl = (sh & 3) ^ ((r >> 1) & 3);
      gload_lds16(Bt + (size_t)(col0 + r) * K + k0 + kh * 32 + cl * 8,
                  (void*)(Bs + (size_t)(is * 256 + (tid & ~63)) * 8));
    }
    __syncthreads();
#pragma unroll
    for (int kh = 0; kh < 2; ++kh) {
      s16x8 af[FM], bfv[FN];
#pragma unroll
      for (int fm = 0; fm < FM; ++fm) af[fm] = *(const s16x8*)(As + kh * (BM * 32) + a_off[fm]);
#pragma unroll
      for (int fn = 0; fn < FN; ++fn) bfv[fn] = *(const s16x8*)(Bs + kh * (BN * 32) + b_off[fn]);
#pragma unroll
      for (int fm = 0; fm < FM; ++fm)
#pragma unroll
        for (int fn = 0; fn < FN; ++fn)
          acc[fm][fn] = mfma16(af[fm], bfv[fn], acc[fm][fn]);
    }
  }

  // epilogue: C elem (row=(lane>>4)*4+ii, col=lane&15) per 16x16 frag
  if constexpr (EPI == 0) {
#pragma unroll
    for (int fn = 0; fn < FN; ++fn) {
      const int j = col0 + wn * WN + fn * 16 + (lane & 15);
      const int which = j >> 9;  // uniform per (wn,fn): 16-blocks never straddle 512
      u16* dst = (which == 0) ? oq : (which == 1) ? ok : ov;
      const float* bias = (which == 0) ? bias0 : (which == 1) ? bias1 : bias2;
      const int v = j & 511;
      const float bj = bias[((v & 63) << 3) | (v >> 6)];
#pragma unroll
      for (int fm = 0; fm < FM; ++fm) {
        const int ibase = row0 + wm * WM + fm * 16 + ((lane >> 4) << 2);
#pragma unroll
        for (int ii = 0; ii < 4; ++ii)
          dst[(size_t)(ibase + ii) * 512 + v] = f2bf(acc[fm][fn][ii] + bj);
      }
    }
  } else {
#pragma unroll
    for (int fn = 0; fn < FN; ++fn) {
      const int j = col0 + wn * WN + fn * 16 + (lane & 15);
      const float bj = bias0[j];
      float s = 0.f, q = 0.f;
#pragma unroll
      for (int fm = 0; fm < FM; ++fm) {
        const int ibase = row0 + wm * WM + fm * 16 + ((lane >> 4) << 2);
        if constexpr (EPI == 1) {
#pragma unroll
          for (int ii = 0; ii < 4; ++ii) {
            int i = ibase + ii;
            float val = acc[fm][fn][ii] + bj + resf[(size_t)i * N + j];
            ob[(size_t)i * N + j] = f2bf(val);
            s += val; q += val * val;
          }
        } else if constexpr (EPI == 2) {
#pragma unroll
          for (int ii = 0; ii < 4; ++ii) {
            int i = ibase + ii;
            float v = acc[fm][fn][ii] + bj;
            ob[(size_t)i * N + j] = f2bf(v > 0.f ? v : 0.f);
          }
        } else {
          const float2 st = stats[j];
#pragma unroll
          for (int ii = 0; ii < 4; ++ii) {
            int i = ibase + ii;
            float val = acc[fm][fn][ii] + bj + (bf2f(resb[(size_t)i * N + j]) * st.x + st.y);
            of[(size_t)i * N + j] = val;
            s += val; q += val * val;
          }
        }
      }
      if constexpr (EPI == 1 || EPI == 3) {  // BM=64, NW_M=1: wave covers all rows
        s += __shfl_xor(s, 16); s += __shfl_xor(s, 32);
        q += __shfl_xor(q, 16); q += __shfl_xor(q, 32);
        if ((lane >> 4) == 0) part[(size_t)brow * 512 + j] = make_float2(s, q);
      }
    }
  }
}

// QKV: 128x96 tile -> grid 768 = exactly 3 blocks/CU (R13-proven)
__global__ __launch_bounds__(256, 3) void qkv_kernel(MegaArgs a) {
  __shared__ __align__(16) u16 smem[(128 + 96) * 64];
  gemm_phase<128, 96, 0, 16>(blockIdx.x, threadIdx.x, smem, a.A0, a.bt_qkv,
      a.bq, a.bk, a.bv, nullptr, nullptr, nullptr, nullptr,
      a.qp, a.kp, a.vpb, nullptr, nullptr, 1536, 512);
}
// O-proj: 64x64 -> grid 768 = 3 blocks/CU
__global__ __launch_bounds__(256, 3) void oproj_kernel(MegaArgs a) {
  __shared__ __align__(16) u16 smem[(64 + 64) * 64];
  gemm_phase<64, 64, 1, 8>(blockIdx.x, threadIdx.x, smem, a.A0, a.bt_o,
      a.bo, nullptr, nullptr, a.h, nullptr, nullptr, a.part1,
      nullptr, nullptr, nullptr, nullptr, a.x1b, 512, 512);
}
// FFN1: 96x128 -> grid 512 = exactly 2 blocks/CU
__global__ __launch_bounds__(256, 2) void ffn1_kernel(MegaArgs a) {
  __shared__ __align__(16) u16 smem[(96 + 128) * 64];
  gemm_phase<96, 128, 2, 8>(blockIdx.x, threadIdx.x, smem, a.x1b, a.bt_1,
      a.b1f, nullptr, nullptr, nullptr, nullptr, nullptr, nullptr,
      nullptr, nullptr, nullptr, nullptr, a.x2, 1024, 512);
}
// FFN2: 64x64 -> grid 768 = 3 blocks/CU
__global__ __launch_bounds__(256, 3) void ffn2_kernel(MegaArgs a) {
  __shared__ __align__(16) u16 smem[(64 + 64) * 64];
  gemm_phase<64, 64, 3, 8>(blockIdx.x, threadIdx.x, smem, a.x2, a.bt_2,
      a.b2, nullptr, nullptr, nullptr, a.x1b, a.stats1, a.part2,
      nullptr, nullptr, nullptr, a.out, nullptr, 512, 1024);
}

// ---------------------------------------------------------------- attention (+ overlapped transposes)
// lb<1024: attn | [1024,1280) Wo operm | [1280,1792) W1 | [1792,2304) W2
__global__ __launch_bounds__(256, 2) void attnx_kernel(MegaArgs a) {
  __shared__ __align__(16) u16 smem[6144];  // Qs 2048 | Vs 2048 | Ps 2048
  const int lb = blockIdx.x, tid = threadIdx.x;
  if (lb >= 1024) {
    float* tile = (float*)smem;
    if (lb < 1280) {  // Wo: dst[j][c] = src[md(c)][j], md(c)=((c&63)<<3)|(c>>6)
      const int t = lb - 1024;
      const int c0 = (t & 15) * 32, j0 = (t >> 4) * 32;
      const int tx = tid & 31, ty = tid >> 5;
#pragma unroll
      for (int i = 0; i < 32; i += 8) {
        int c = c0 + ty + i;
        int md = ((c & 63) << 3) | (c >> 6);
        tile[(ty + i) * 33 + tx] = a.Wo[(size_t)md * 512 + j0 + tx];
      }
      __syncthreads();
#pragma unroll
      for (int i = 0; i < 32; i += 8)
        a.bt_o[(size_t)(j0 + ty + i) * 512 + c0 + tx] = f2bf(tile[tx * 33 + ty + i]);
    } else if (lb < 1792) {  // W1 plain: C=1024 -> bt_1[1024][512]
      const int t = lb - 1280;
      tr_plain(a.W1, a.bt_1, 1024, 512, (t & 31) * 32, (t >> 5) * 32, tid, tile);
    } else {  // W2 plain: C=512 -> bt_2[512][1024]
      const int t = lb - 1792;
      tr_plain(a.W2, a.bt_2, 512, 1024, (t & 15) * 32, (t >> 4) * 32, tid, tile);
    }
    return;
  }
  u16* Qs = smem;
  u16* Vs = smem + 2048;
  u16* PsB = smem + 4096;
  const int rb = lb & 7, hh = (lb >> 3) & 7, b = lb >> 6;
  const int base = a.starts[b], nb = a.starts[b + 1] - base;
  const int r0 = rb * 64;
  if (r0 >= nb) return;
  const int lane = tid & 63, wv = tid >> 6;
  const int g = lane >> 4;
  const int rloc = r0 + wv * 16 + (lane & 15);
  const u16* krow = a.kp + (size_t)(base + rloc) * 512 + hh * 64 + (g << 3);
  s16x8 ak0 = *(const s16x8*)(krow);
  s16x8 ak1 = *(const s16x8*)(krow + 32);
  f32x4 acc_av[4] = {};
  float rs[4] = {0.f, 0.f, 0.f, 0.f};
  u16* Pw = PsB + wv * 512;
  const int vm = ((tid & 63) >> 3) * 4 + ((tid >> 1) & 3);
  const int vf = wv * 16 + (tid & 1) * 8;

  for (int m0 = 0; m0 < nb; m0 += 32) {
    __syncthreads();
    { int r = tid >> 3, cl = (tid & 7) ^ (r & 7);
      gload_lds16(a.qp + (size_t)(base + m0 + r) * 512 + hh * 64 + cl * 8,
                  (void*)(Qs + (size_t)(tid & ~63) * 8)); }
    { gload_lds16(a.vpb + (size_t)(base + m0 + vm) * 512 + hh * 64 + vf,
                  (void*)(Vs + (size_t)(tid & ~63) * 8)); }
    __syncthreads();
#pragma unroll
    for (int ch = 0; ch < 2; ++ch) {
      f32x4 s = {};
#pragma unroll
      for (int kc = 0; kc < 2; ++kc) {
        const int mr = ch * 16 + (lane & 15);
        const int chunk = kc * 4 + g;
        s16x8 bq = *(const s16x8*)(Qs + mr * 64 + ((chunk ^ (mr & 7)) << 3));
        s = mfma16(kc == 0 ? ak0 : ak1, bq, s);
      }
      const int mg = m0 + ch * 16 + (lane & 15);
      const bool valid = mg < nb;
      const int c = ch * 16 + (lane & 15);
#pragma unroll
      for (int ii = 0; ii < 4; ++ii) {
        float pv = valid ? __expf(s[ii] * 0.125f) : 0.f;
        rs[ii] += pv;
        const int r = (g << 2) + ii;
        Pw[r * 32 + (((c >> 3) ^ ((r >> 1) & 3)) << 3) + (c & 7)] = f2bf(pv);
      }
    }
    const int pr = lane & 15;
    s16x8 pa = *(const s16x8*)(Pw + pr * 32 + ((g ^ ((pr >> 1) & 3)) << 3));
#pragma unroll
    for (int fb = 0; fb < 4; ++fb) {
      s16x8 bv = v_frag_tr(Vs, fb * 512 + g * 128 + (lane & 15));
      acc_av[fb] = mfma16(pa, bv, acc_av[fb]);
    }
  }
#pragma unroll
  for (int ii = 0; ii < 4; ++ii) {
    float v = rs[ii];
    v += __shfl_xor(v, 1); v += __shfl_xor(v, 2);
    v += __shfl_xor(v, 4); v += __shfl_xor(v, 8);
    rs[ii] = 1.f / v;
  }
#pragma unroll
  for (int ii = 0; ii < 4; ++ii) {
    const int rl = r0 + wv * 16 + (g << 2) + ii;
    if (rl < nb) {
      const size_t node = base + rl;
#pragma unroll
      for (int fb = 0; fb < 4; ++fb) {
        const int f = fb * 16 + (lane & 15);
        a.A0[node * 512 + hh * 64 + f] = f2bf(acc_av[fb][ii] * rs[ii]);  // av
      }
    }
  }
}

// ---------------------------------------------------------------- batchnorm (R7-proven)
// Parallel finalize: 16 blocks x 32 cols; thread (rg,lc) sums 12 of 96 rows.
__global__ void bn_fin_kernel(const float2* __restrict__ part, const float* __restrict__ g,
                              const float* __restrict__ be, float2* __restrict__ stats) {
  __shared__ float red_s[8][32];
  __shared__ float red_q[8][32];
  const int t = threadIdx.x;
  const int lc = t & 31, rg = t >> 5;
  const int c = blockIdx.x * 32 + lc;
  float s = 0.f, q = 0.f;
#pragma unroll
  for (int k = 0; k < 12; ++k) {
    float2 v = part[(size_t)(rg + 8 * k) * 512 + c];
    s += v.x; q += v.y;
  }
  red_s[rg][lc] = s; red_q[rg][lc] = q;
  __syncthreads();
  if (rg == 0) {
#pragma unroll
    for (int r = 1; r < 8; ++r) { s += red_s[r][lc]; q += red_q[r][lc]; }
    const float inv = 1.f / (float)N_NODES;
    float m = s * inv, var = q * inv - m * m;
    float sc = g[c] * rsqrtf(var + EPSV);
    stats[c] = make_float2(sc, be[c] - m * sc);
  }
}

// Fold BN1 into FFN1 weights: bt_1[j][c] *= sc1[c]; b1f[j] = b1[j] + sum ofs1*w.
__global__ void bn1_fold_kernel(MegaArgs a) {
  const int tid = threadIdx.x, lane = tid & 63, wv = tid >> 6;
  const int j = blockIdx.x * 4 + wv;
  u16* row = a.bt_1 + (size_t)j * 512 + lane * 8;
  s16x8 v = *(const s16x8*)row;
  s16x8 o;
  float dot = 0.f;
#pragma unroll
  for (int t = 0; t < 8; ++t) {
    float2 st = a.stats1[lane * 8 + t];
    float w = bf2f((u16)v[t]);
    o[t] = (short)f2bf(w * st.x);
    dot += w * st.y;
  }
  *(s16x8*)row = o;
  dot += __shfl_xor(dot, 1);  dot += __shfl_xor(dot, 2);
  dot += __shfl_xor(dot, 4);  dot += __shfl_xor(dot, 8);
  dot += __shfl_xor(dot, 16); dot += __shfl_xor(dot, 32);
  if (lane == 0) a.b1f[j] = a.b1[j] + dot;
}

__global__ void bn_apply_f32_kernel(float* __restrict__ x, const float2* __restrict__ stats) {
  const int i = (blockIdx.x * 256 + threadIdx.x) * 4;
  float4 v = *(float4*)(x + i);
  const int c = i & 511;
  float2 sa = stats[c], sb = stats[c + 1], sc2 = stats[c + 2], sd = stats[c + 3];
  *(float4*)(x + i) = make_float4(v.x * sa.x + sa.y, v.y * sb.x + sb.y,
                                  v.z * sc2.x + sc2.y, v.w * sd.x + sd.y);
}

// ---------------------------------------------------------------- launch
extern "C" void kernel_launch(void* const* d_in, const int* in_sizes, int n_in,
                              void* d_out, int out_size, void* d_ws, size_t ws_size,
                              hipStream_t stream) {
  (void)in_sizes; (void)n_in; (void)out_size; (void)ws_size;
  char* ws = (char*)d_ws;
  size_t off = 0;
  auto alloc = [&](size_t bytes) -> void* {
    void* p = ws + off;
    off += (bytes + 255) & ~(size_t)255;
    return p;
  };

  MegaArgs a;
  a.h   = (const float*)d_in[0];
  a.batch = (const int*)d_in[1];
  a.Wq = (const float*)d_in[2];  a.bq = (const float*)d_in[3];
  a.Wk = (const float*)d_in[4];  a.bk = (const float*)d_in[5];
  a.Wv = (const float*)d_in[6];  a.bv = (const float*)d_in[7];
  a.Wo = (const float*)d_in[8];  a.bo = (const float*)d_in[9];
  a.g1 = (const float*)d_in[10]; a.be1 = (const float*)d_in[11];
  a.W1 = (const float*)d_in[12]; a.b1 = (const float*)d_in[13];
  a.W2 = (const float*)d_in[14]; a.b2 = (const float*)d_in[15];
  a.g2 = (const float*)d_in[16]; a.be2 = (const float*)d_in[17];
  a.out = (float*)d_out;

  a.starts = (int*)alloc(17 * 4);
  a.part1  = (float2*)alloc((size_t)96 * 512 * sizeof(float2));
  a.part2  = (float2*)alloc((size_t)96 * 512 * sizeof(float2));
  a.stats1 = (float2*)alloc(512 * sizeof(float2));
  a.stats2 = (float2*)alloc(512 * sizeof(float2));
  a.b1f    = (float*)alloc(1024 * sizeof(float));
  a.bt_qkv = (u16*)alloc((size_t)1536 * 512 * 2);
  a.bt_o   = (u16*)alloc((size_t)512 * 512 * 2);
  a.bt_1   = (u16*)alloc((size_t)1024 * 512 * 2);
  a.bt_2   = (u16*)alloc((size_t)512 * 1024 * 2);
  a.A0  = (u16*)alloc((size_t)N_NODES * 512 * 2);          // h bf16; reused as av
  a.qp  = (u16*)alloc((size_t)(N_NODES + 64) * 512 * 2);   // with kp reused as x2
  a.kp  = (u16*)alloc((size_t)(N_NODES + 64) * 512 * 2);
  a.vpb = (u16*)alloc((size_t)(N_NODES + 64) * 512 * 2);
  a.x1b = (u16*)alloc((size_t)N_NODES * 512 * 2);          // pre-BN1 value (bf16)
  a.x2  = a.qp;  // qp+kp contiguous = 12.7MB >= 12.6MB

  prep_kernel<<<3841, 256, 0, stream>>>(a);
  qkv_kernel<<<768, 256, 0, stream>>>(a);
  attnx_kernel<<<2304, 256, 0, stream>>>(a);
  oproj_kernel<<<768, 256, 0, stream>>>(a);
  bn_fin_kernel<<<16, 256, 0, stream>>>(a.part1, a.g1, a.be1, a.stats1);
  bn1_fold_kernel<<<256, 256, 0, stream>>>(a);
  ffn1_kernel<<<512, 256, 0, stream>>>(a);
  ffn2_kernel<<<768, 256, 0, stream>>>(a);
  bn_fin_kernel<<<16, 256, 0, stream>>>(a.part2, a.g2, a.be2, a.stats2);
  bn_apply_f32_kernel<<<3072, 256, 0, stream>>>(a.out, a.stats2);
}